// Round 1
// baseline (6485.907 us; speedup 1.0000x reference)
//
#include <hip/hip_runtime.h>
#include <cstdint>

#define BB 8192
#define TT 50
#define FF 24

__device__ __forceinline__ float sigf(float x){ return 1.0f/(1.0f + __expf(-x)); }

// 4 fp32 FMA chunks for 2 columns (wA,wB) x 2 rows (u,v) -> 4 acc chains (ILP)
#define FMA_CHUNK(u,v,kb) \
  a0 = fmaf((u).x, wA[(kb)+0], a0); a1 = fmaf((u).x, wB[(kb)+0], a1); \
  a2 = fmaf((v).x, wA[(kb)+0], a2); a3 = fmaf((v).x, wB[(kb)+0], a3); \
  a0 = fmaf((u).y, wA[(kb)+1], a0); a1 = fmaf((u).y, wB[(kb)+1], a1); \
  a2 = fmaf((v).y, wA[(kb)+1], a2); a3 = fmaf((v).y, wB[(kb)+1], a3); \
  a0 = fmaf((u).z, wA[(kb)+2], a0); a1 = fmaf((u).z, wB[(kb)+2], a1); \
  a2 = fmaf((v).z, wA[(kb)+2], a2); a3 = fmaf((v).z, wB[(kb)+2], a3); \
  a0 = fmaf((u).w, wA[(kb)+3], a0); a1 = fmaf((u).w, wB[(kb)+3], a1); \
  a2 = fmaf((v).w, wA[(kb)+3], a2); a3 = fmaf((v).w, wB[(kb)+3], a3);

// ---------------- LSTM1: x[B][T][24] -> h1seq[T][B][64] ----------------
// grid 256, block 512. 32 rows/block. 8 waves = 4 row-groups x 2 gate-pair waves.
// Each lane owns 2 gate-columns (weights resident in VGPRs, 176 regs).
__global__ __launch_bounds__(512,2) void lstm1_k(
    const float* __restrict__ x, const float* __restrict__ W1,
    const float* __restrict__ U1, const float* __restrict__ b1,
    float* __restrict__ h1seq)
{
  constexpr int HS = 72, ZS = 72;  // padded strides: all LDS access <=2-way/bank (free)
  __shared__ float xs[32*FF];
  __shared__ float hs[32*HS];
  __shared__ float zs[4][4*8*ZS];  // [rowgroup][gate][row8][72]

  const int tid  = threadIdx.x;
  const int wave = tid >> 6, lane = tid & 63;
  const int rg = wave >> 1, gp = wave & 1;     // row-group 0..3, gate-pair 0..1
  const int g  = gp*2 + (lane >> 5);           // gate 0..3 (i,f,g,o)
  const int chA = 2*(lane & 31);               // channel pair chA, chA+1
  const int col = g*64 + chA;                  // column in [256]
  const int b0 = blockIdx.x * 32;

  float wA[88], wB[88];
#pragma unroll
  for (int k=0;k<24;k++){ wA[k]    = W1[k*256+col]; wB[k]    = W1[k*256+col+1]; }
#pragma unroll
  for (int k=0;k<64;k++){ wA[24+k] = U1[k*256+col]; wB[24+k] = U1[k*256+col+1]; }
  const float bA = b1[col], bB = b1[col+1];

  // gate-math role: this wave handles row-group rg, channel half gp
  const int gls = lane >> 5;                   // row parity
  const int gch = gp*32 + (lane & 31);         // h channel 0..63
  float c_[4] = {0.f,0.f,0.f,0.f};

  for (int i=tid; i<32*HS; i+=512) hs[i] = 0.f;
  __syncthreads();

#pragma unroll 1
  for (int t=0; t<TT; ++t){
    // stage x[rows, t, 0:24]
    for (int i=tid; i<32*FF; i+=512){
      int r = i/FF, f = i - r*FF;
      xs[i] = x[((size_t)(b0+r)*TT + t)*FF + f];
    }
    __syncthreads();
    // dot phase: 8 rows, unrolled by 2 for 4 independent FMA chains
#pragma unroll 1
    for (int lr=0; lr<8; lr+=2){
      const int gr0 = rg*8 + lr, gr1 = gr0 + 1;
      float a0=bA, a1=bB, a2=bA, a3=bB;
      const float4* xu = (const float4*)&xs[gr0*FF];
      const float4* xv = (const float4*)&xs[gr1*FF];
#pragma unroll
      for (int j=0;j<6;++j){ float4 u = xu[j], v = xv[j]; FMA_CHUNK(u,v,4*j) }
      const float4* hu = (const float4*)&hs[gr0*HS];
      const float4* hv = (const float4*)&hs[gr1*HS];
#pragma unroll
      for (int j=0;j<16;++j){ float4 u = hu[j], v = hv[j]; FMA_CHUNK(u,v,24+4*j) }
      *(float2*)&zs[rg][(g*8+lr  )*ZS + chA] = make_float2(a0,a1);
      *(float2*)&zs[rg][(g*8+lr+1)*ZS + chA] = make_float2(a2,a3);
    }
    __syncthreads();
    // gate math: i,f sigmoid; g relu; o sigmoid; h = o*relu(c)
#pragma unroll
    for (int it=0; it<4; ++it){
      const int lr = 2*it + gls;
      const float zi = zs[rg][(0*8+lr)*ZS + gch];
      const float zf = zs[rg][(1*8+lr)*ZS + gch];
      const float zg = zs[rg][(2*8+lr)*ZS + gch];
      const float zo = zs[rg][(3*8+lr)*ZS + gch];
      const float ig = sigf(zi), fg = sigf(zf);
      const float gg = fmaxf(zg, 0.f), og = sigf(zo);
      const float cn = fg*c_[it] + ig*gg;
      c_[it] = cn;
      const float hn = og * fmaxf(cn, 0.f);
      const int r = rg*8 + lr;
      hs[r*HS + gch] = hn;
      h1seq[(size_t)t*BB*64 + (size_t)(b0+r)*64 + gch] = hn;
    }
    __syncthreads();
  }
}

// ---------------- LSTM2: h1seq[T][B][64] -> zlat[B][32] ----------------
// grid 256, block 512. Each wave self-contained: 4 rows, all 128 z-cols (2/lane).
__global__ __launch_bounds__(512,2) void lstm2_k(
    const float* __restrict__ h1seq, const float* __restrict__ W2,
    const float* __restrict__ U2, const float* __restrict__ b2,
    float* __restrict__ zlat)
{
  __shared__ float h1s[32*64];
  __shared__ float h2s[8*4*32];
  __shared__ float zw[8*2*128];

  const int tid = threadIdx.x;
  const int wave = tid>>6, lane = tid&63;
  const int rbase = wave*4;
  const int cA = 2*lane;                 // z-cols cA, cA+1 (same gate)
  const int b0 = blockIdx.x*32;

  float wA[96], wB[96];
#pragma unroll
  for (int k=0;k<64;k++){ wA[k]    = W2[k*128+cA]; wB[k]    = W2[k*128+cA+1]; }
#pragma unroll
  for (int k=0;k<32;k++){ wA[64+k] = U2[k*128+cA]; wB[64+k] = U2[k*128+cA+1]; }
  const float bA = b2[cA], bB = b2[cA+1];

  const int gls = lane>>5, gch = lane&31;
  float c_[2] = {0.f, 0.f};

  for (int i=tid;i<8*4*32;i+=512) h2s[i]=0.f;
  __syncthreads();

#pragma unroll 1
  for (int t=0;t<TT;++t){
    for (int i=tid;i<32*64;i+=512) h1s[i] = h1seq[(size_t)t*BB*64 + (size_t)b0*64 + i];
    __syncthreads();
#pragma unroll 1
    for (int lr=0; lr<4; lr+=2){
      float a0=bA,a1=bB,a2=bA,a3=bB;
      const float4* xu = (const float4*)&h1s[(rbase+lr  )*64];
      const float4* xv = (const float4*)&h1s[(rbase+lr+1)*64];
#pragma unroll
      for (int j=0;j<16;++j){ float4 u=xu[j], v=xv[j]; FMA_CHUNK(u,v,4*j) }
      const float4* hu = (const float4*)&h2s[(wave*4+lr  )*32];
      const float4* hv = (const float4*)&h2s[(wave*4+lr+1)*32];
#pragma unroll
      for (int j=0;j<8;++j){ float4 u=hu[j], v=hv[j]; FMA_CHUNK(u,v,64+4*j) }
      *(float2*)&zw[(wave*2+0)*128 + cA] = make_float2(a0,a1);
      *(float2*)&zw[(wave*2+1)*128 + cA] = make_float2(a2,a3);
      __syncthreads();
      {
        const int lrow = lr + gls;
        const float zi = zw[(wave*2+gls)*128 + 0  + gch];
        const float zf = zw[(wave*2+gls)*128 + 32 + gch];
        const float zg = zw[(wave*2+gls)*128 + 64 + gch];
        const float zo = zw[(wave*2+gls)*128 + 96 + gch];
        const float ig=sigf(zi), fg=sigf(zf), gg=fmaxf(zg,0.f), og=sigf(zo);
        const int ci = lr>>1;
        const float cn = fg*c_[ci] + ig*gg;
        c_[ci] = cn;
        const float hn = og*fmaxf(cn,0.f);
        h2s[(wave*4+lrow)*32 + gch] = hn;
        if (t == TT-1) zlat[(size_t)(b0+rbase+lrow)*32 + gch] = hn;
      }
      __syncthreads();
    }
  }
}

// ---------- LSTM3 + fused Dense: zlat[B][32] -> out[B][T][24] ----------
// RepeatVector input is constant over t: fold z into the state vector (z||h).
// Dense rides on h[t-1] held in LDS; epilogue pass handles t=49.
__global__ __launch_bounds__(512,2) void lstm3_k(
    const float* __restrict__ zlat, const float* __restrict__ W3,
    const float* __restrict__ U3, const float* __restrict__ b3,
    const float* __restrict__ Wd, const float* __restrict__ bd,
    float* __restrict__ out)
{
  constexpr int HS = 104, ZS = 72;   // state row: [z(32), h(64), pad(8)]
  __shared__ float hs[32*HS];
  __shared__ float zs[4][4*8*ZS];

  const int tid = threadIdx.x, wave = tid>>6, lane = tid&63;
  const int rg = wave>>1, gp = wave&1;
  const int g = gp*2 + (lane>>5);
  const int chA = 2*(lane&31);
  const int col = g*64 + chA;
  const int b0 = blockIdx.x*32;

  float wA[96], wB[96];
#pragma unroll
  for (int k=0;k<32;k++){ wA[k]    = W3[k*256+col]; wB[k]    = W3[k*256+col+1]; }
#pragma unroll
  for (int k=0;k<64;k++){ wA[32+k] = U3[k*256+col]; wB[32+k] = U3[k*256+col+1]; }
  const float bA = b3[col], bB = b3[col+1];

  const int gls = lane>>5, gch = gp*32 + (lane&31);
  float c_[4] = {0.f,0.f,0.f,0.f};

  // dense role: lanes 0..47: out-col = gp*12 + lane/4, k-quarter = lane&3
  const int kq = lane & 3;
  const int dactive = (lane < 48);
  const int dcol = dactive ? (gp*12 + (lane>>2)) : 0;
  float wd[16];
#pragma unroll
  for (int j=0;j<16;++j) wd[j] = Wd[(kq*16+j)*24 + dcol];
  const float bdv = bd[dcol];

  for (int i=tid;i<32*32;i+=512){ int r=i>>5, k=i&31; hs[r*HS+k] = zlat[(size_t)b0*32 + i]; }
  for (int i=tid;i<32*64;i+=512){ int r=i>>6, k=i&63; hs[r*HS+32+k] = 0.f; }
  __syncthreads();

#pragma unroll 1
  for (int t=0;t<=TT;++t){
    if (t < TT){
#pragma unroll 1
      for (int lr=0;lr<8;lr+=2){
        const int gr0 = rg*8+lr, gr1 = gr0+1;
        float a0=bA,a1=bB,a2=bA,a3=bB;
        const float4* su = (const float4*)&hs[gr0*HS];
        const float4* sv = (const float4*)&hs[gr1*HS];
#pragma unroll
        for (int j=0;j<24;++j){ float4 u=su[j], v=sv[j]; FMA_CHUNK(u,v,4*j) }
        *(float2*)&zs[rg][(g*8+lr  )*ZS+chA] = make_float2(a0,a1);
        *(float2*)&zs[rg][(g*8+lr+1)*ZS+chA] = make_float2(a2,a3);
      }
    }
    if (t > 0){
      const int tw = t-1;
#pragma unroll 1
      for (int lr=0;lr<8;++lr){
        const int r = rg*8+lr;
        const float4* hp = (const float4*)&hs[r*HS+32];
        float d = 0.f;
#pragma unroll
        for (int j=0;j<4;++j){
          float4 u = hp[kq*4+j];
          d = fmaf(u.x, wd[4*j+0], d);
          d = fmaf(u.y, wd[4*j+1], d);
          d = fmaf(u.z, wd[4*j+2], d);
          d = fmaf(u.w, wd[4*j+3], d);
        }
        d += __shfl_xor(d,1);
        d += __shfl_xor(d,2);
        if (dactive && kq==0)
          out[((size_t)(b0+r)*TT + tw)*FF + dcol] = d + bdv;
      }
    }
    __syncthreads();
    if (t < TT){
#pragma unroll
      for (int it=0; it<4; ++it){
        const int lr = 2*it + gls;
        const float zi = zs[rg][(0*8+lr)*ZS+gch];
        const float zf = zs[rg][(1*8+lr)*ZS+gch];
        const float zg = zs[rg][(2*8+lr)*ZS+gch];
        const float zo = zs[rg][(3*8+lr)*ZS+gch];
        const float ig=sigf(zi), fg=sigf(zf), gg=fmaxf(zg,0.f), og=sigf(zo);
        const float cn = fg*c_[it] + ig*gg;
        c_[it]=cn;
        hs[(rg*8+lr)*HS + 32 + gch] = og*fmaxf(cn,0.f);
      }
    }
    __syncthreads();
  }
}

extern "C" void kernel_launch(void* const* d_in, const int* in_sizes, int n_in,
                              void* d_out, int out_size, void* d_ws, size_t ws_size,
                              hipStream_t stream){
  const float* x  = (const float*)d_in[0];
  const float* W1 = (const float*)d_in[1];
  const float* U1 = (const float*)d_in[2];
  const float* b1 = (const float*)d_in[3];
  const float* W2 = (const float*)d_in[4];
  const float* U2 = (const float*)d_in[5];
  const float* b2 = (const float*)d_in[6];
  const float* W3 = (const float*)d_in[7];
  const float* U3 = (const float*)d_in[8];
  const float* b3 = (const float*)d_in[9];
  const float* Wd = (const float*)d_in[10];
  const float* bd = (const float*)d_in[11];
  float* out = (float*)d_out;
  float* h1seq = (float*)d_ws;                      // [T][B][64] = 104.9 MB
  float* zlat  = h1seq + (size_t)TT*BB*64;          // [B][32]    = 1.0 MB

  hipLaunchKernelGGL(lstm1_k, dim3(256), dim3(512), 0, stream, x, W1, U1, b1, h1seq);
  hipLaunchKernelGGL(lstm2_k, dim3(256), dim3(512), 0, stream, h1seq, W2, U2, b2, zlat);
  hipLaunchKernelGGL(lstm3_k, dim3(256), dim3(512), 0, stream, zlat, W3, U3, b3, Wd, bd, out);
}

// Round 2
// 4898.524 us; speedup vs baseline: 1.3241x; 1.3241x over previous
//
#include <hip/hip_runtime.h>
#include <cstdint>

#define BB 8192
#define TT 50
#define FF 24

__device__ __forceinline__ float sigf(float x){ return 1.0f/(1.0f + __expf(-x)); }

// 4 fp32 FMA chunks for 2 columns (WA,WB) x 2 rows (u,v) -> 4 acc chains (ILP)
#define FMA_CHUNK(u,v,kb,WA,WB) \
  a0 = fmaf((u).x, WA[(kb)+0], a0); a1 = fmaf((u).x, WB[(kb)+0], a1); \
  a2 = fmaf((v).x, WA[(kb)+0], a2); a3 = fmaf((v).x, WB[(kb)+0], a3); \
  a0 = fmaf((u).y, WA[(kb)+1], a0); a1 = fmaf((u).y, WB[(kb)+1], a1); \
  a2 = fmaf((v).y, WA[(kb)+1], a2); a3 = fmaf((v).y, WB[(kb)+1], a3); \
  a0 = fmaf((u).z, WA[(kb)+2], a0); a1 = fmaf((u).z, WB[(kb)+2], a1); \
  a2 = fmaf((v).z, WA[(kb)+2], a2); a3 = fmaf((v).z, WB[(kb)+2], a3); \
  a0 = fmaf((u).w, WA[(kb)+3], a0); a1 = fmaf((u).w, WB[(kb)+3], a1); \
  a2 = fmaf((v).w, WA[(kb)+3], a2); a3 = fmaf((v).w, WB[(kb)+3], a3);

// ---------------- LSTM1: x[B][T][24] -> h1seq[T][B][64] ----------------
// grid 256, block 512. 32 rows/block. 8 waves = 4 row-groups x 2 gate-pair waves.
// Each lane owns 2 gate-columns; weights resident in VGPRs (176 regs).
// __launch_bounds__(512,1): a 512-thr block forces 2 waves/SIMD co-resident,
// so VGPR cap is 256 — enough for the weight arrays with NO spill.
// ((512,2) empirically capped at 128 VGPRs -> 5.9 GB of scratch-spill HBM reads.)
__global__ __launch_bounds__(512,1) void lstm1_k(
    const float* __restrict__ x, const float* __restrict__ W1,
    const float* __restrict__ U1, const float* __restrict__ b1,
    float* __restrict__ h1seq)
{
  constexpr int HS = 72, ZS = 72;  // padded strides
  __shared__ float xs[32*FF];
  __shared__ float hs[32*HS];
  __shared__ float zs[4][4*8*ZS];  // [rowgroup][gate][row8][72]

  const int tid  = threadIdx.x;
  const int wave = tid >> 6, lane = tid & 63;
  const int rg = wave >> 1, gp = wave & 1;     // row-group 0..3, gate-pair 0..1
  const int g  = gp*2 + (lane >> 5);           // gate 0..3 (i,f,g,o)
  const int chA = 2*(lane & 31);               // channel pair chA, chA+1
  const int col = g*64 + chA;                  // column in [256]
  const int b0 = blockIdx.x * 32;

  float wA[88], wB[88];
#pragma unroll
  for (int k=0;k<24;k++){ wA[k]    = W1[k*256+col]; wB[k]    = W1[k*256+col+1]; }
#pragma unroll
  for (int k=0;k<64;k++){ wA[24+k] = U1[k*256+col]; wB[24+k] = U1[k*256+col+1]; }
  const float bA = b1[col], bB = b1[col+1];

  const int gls = lane >> 5;                   // row parity
  const int gch = gp*32 + (lane & 31);         // h channel 0..63
  float c_[4] = {0.f,0.f,0.f,0.f};

  for (int i=tid; i<32*HS; i+=512) hs[i] = 0.f;
  __syncthreads();

#pragma unroll 1
  for (int t=0; t<TT; ++t){
    // stage x[rows, t, 0:24]
    for (int i=tid; i<32*FF; i+=512){
      int r = i/FF, f = i - r*FF;
      xs[i] = x[((size_t)(b0+r)*TT + t)*FF + f];
    }
    __syncthreads();
#pragma unroll 1
    for (int lr=0; lr<8; lr+=2){
      const int gr0 = rg*8 + lr, gr1 = gr0 + 1;
      float a0=bA, a1=bB, a2=bA, a3=bB;
      const float4* xu = (const float4*)&xs[gr0*FF];
      const float4* xv = (const float4*)&xs[gr1*FF];
#pragma unroll
      for (int j=0;j<6;++j){ float4 u = xu[j], v = xv[j]; FMA_CHUNK(u,v,4*j,wA,wB) }
      const float4* hu = (const float4*)&hs[gr0*HS];
      const float4* hv = (const float4*)&hs[gr1*HS];
#pragma unroll
      for (int j=0;j<16;++j){ float4 u = hu[j], v = hv[j]; FMA_CHUNK(u,v,24+4*j,wA,wB) }
      *(float2*)&zs[rg][(g*8+lr  )*ZS + chA] = make_float2(a0,a1);
      *(float2*)&zs[rg][(g*8+lr+1)*ZS + chA] = make_float2(a2,a3);
    }
    __syncthreads();
    // gate math: i,f sigmoid; g relu; o sigmoid; h = o*relu(c)
#pragma unroll
    for (int it=0; it<4; ++it){
      const int lr = 2*it + gls;
      const float zi = zs[rg][(0*8+lr)*ZS + gch];
      const float zf = zs[rg][(1*8+lr)*ZS + gch];
      const float zg = zs[rg][(2*8+lr)*ZS + gch];
      const float zo = zs[rg][(3*8+lr)*ZS + gch];
      const float ig = sigf(zi), fg = sigf(zf);
      const float gg = fmaxf(zg, 0.f), og = sigf(zo);
      const float cn = fg*c_[it] + ig*gg;
      c_[it] = cn;
      const float hn = og * fmaxf(cn, 0.f);
      const int r = rg*8 + lr;
      hs[r*HS + gch] = hn;
      h1seq[(size_t)t*BB*64 + (size_t)(b0+r)*64 + gch] = hn;
    }
    __syncthreads();
  }
}

// ---------------- LSTM2: h1seq[T][B][64] -> zlat[B][32] ----------------
// grid 256, block 512. Each wave self-contained: 4 rows, all 128 z-cols (2/lane).
__global__ __launch_bounds__(512,1) void lstm2_k(
    const float* __restrict__ h1seq, const float* __restrict__ W2,
    const float* __restrict__ U2, const float* __restrict__ b2,
    float* __restrict__ zlat)
{
  __shared__ float h1s[32*64];
  __shared__ float h2s[8*4*32];
  __shared__ float zw[8*2*128];

  const int tid = threadIdx.x;
  const int wave = tid>>6, lane = tid&63;
  const int rbase = wave*4;
  const int cA = 2*lane;                 // z-cols cA, cA+1 (same gate)
  const int b0 = blockIdx.x*32;

  float wA[96], wB[96];
#pragma unroll
  for (int k=0;k<64;k++){ wA[k]    = W2[k*128+cA]; wB[k]    = W2[k*128+cA+1]; }
#pragma unroll
  for (int k=0;k<32;k++){ wA[64+k] = U2[k*128+cA]; wB[64+k] = U2[k*128+cA+1]; }
  const float bA = b2[cA], bB = b2[cA+1];

  const int gls = lane>>5, gch = lane&31;
  float c_[2] = {0.f, 0.f};

  for (int i=tid;i<8*4*32;i+=512) h2s[i]=0.f;
  __syncthreads();

#pragma unroll 1
  for (int t=0;t<TT;++t){
    for (int i=tid;i<32*64;i+=512) h1s[i] = h1seq[(size_t)t*BB*64 + (size_t)b0*64 + i];
    __syncthreads();
#pragma unroll 1
    for (int lr=0; lr<4; lr+=2){
      float a0=bA,a1=bB,a2=bA,a3=bB;
      const float4* xu = (const float4*)&h1s[(rbase+lr  )*64];
      const float4* xv = (const float4*)&h1s[(rbase+lr+1)*64];
#pragma unroll
      for (int j=0;j<16;++j){ float4 u=xu[j], v=xv[j]; FMA_CHUNK(u,v,4*j,wA,wB) }
      const float4* hu = (const float4*)&h2s[(wave*4+lr  )*32];
      const float4* hv = (const float4*)&h2s[(wave*4+lr+1)*32];
#pragma unroll
      for (int j=0;j<8;++j){ float4 u=hu[j], v=hv[j]; FMA_CHUNK(u,v,64+4*j,wA,wB) }
      *(float2*)&zw[(wave*2+0)*128 + cA] = make_float2(a0,a1);
      *(float2*)&zw[(wave*2+1)*128 + cA] = make_float2(a2,a3);
      __syncthreads();
      {
        const int lrow = lr + gls;
        const float zi = zw[(wave*2+gls)*128 + 0  + gch];
        const float zf = zw[(wave*2+gls)*128 + 32 + gch];
        const float zg = zw[(wave*2+gls)*128 + 64 + gch];
        const float zo = zw[(wave*2+gls)*128 + 96 + gch];
        const float ig=sigf(zi), fg=sigf(zf), gg=fmaxf(zg,0.f), og=sigf(zo);
        const int ci = lr>>1;
        const float cn = fg*c_[ci] + ig*gg;
        c_[ci] = cn;
        const float hn = og*fmaxf(cn,0.f);
        h2s[(wave*4+lrow)*32 + gch] = hn;
        if (t == TT-1) zlat[(size_t)(b0+rbase+lrow)*32 + gch] = hn;
      }
      __syncthreads();
    }
  }
}

// ---------- LSTM3 + fused Dense: zlat[B][32] -> out[B][T][24] ----------
// RepeatVector input is constant over t: b3 + z@W3 is loop-invariant.
// Precompute it ONCE per block into LDS (zw3[32][256]); the t-loop then only
// does h@U3 (K=64 -> 128 resident weight regs, 1024 FMA/lane/t).
__global__ __launch_bounds__(512,1) void lstm3_k(
    const float* __restrict__ zlat, const float* __restrict__ W3,
    const float* __restrict__ U3, const float* __restrict__ b3,
    const float* __restrict__ Wd, const float* __restrict__ bd,
    float* __restrict__ out)
{
  constexpr int HS = 72, ZS = 72;
  __shared__ float hs[32*HS];        // h state per row
  __shared__ float zs[4][4*8*ZS];    // gate pre-activations
  __shared__ float zw3[32*256];      // loop-invariant b3 + z@W3
  __shared__ float zstage[32*36];    // staged z (stride 36: 16B-aligned rows)

  const int tid = threadIdx.x, wave = tid>>6, lane = tid&63;
  const int rg = wave>>1, gp = wave&1;
  const int g = gp*2 + (lane>>5);
  const int chA = 2*(lane&31);
  const int col = g*64 + chA;
  const int b0 = blockIdx.x*32;

  float wA[64], wB[64];              // U3 only
#pragma unroll
  for (int k=0;k<64;k++){ wA[k] = U3[k*256+col]; wB[k] = U3[k*256+col+1]; }

  // dense role: lanes 0..47: out-col = gp*12 + lane/4, k-quarter = lane&3
  const int kq = lane & 3;
  const int dactive = (lane < 48);
  const int dcol = dactive ? (gp*12 + (lane>>2)) : 0;
  float wd[16];
#pragma unroll
  for (int j=0;j<16;++j) wd[j] = Wd[(kq*16+j)*24 + dcol];
  const float bdv = bd[dcol];

  for (int i=tid;i<32*32;i+=512){ int r=i>>5, k=i&31; zstage[r*36+k] = zlat[(size_t)b0*32 + i]; }
  for (int i=tid;i<32*HS;i+=512) hs[i] = 0.f;
  __syncthreads();

  // precompute zw3 = b3 + z @ W3 (once)
  {
    float wzA[32], wzB[32];
#pragma unroll
    for (int k=0;k<32;k++){ wzA[k] = W3[k*256+col]; wzB[k] = W3[k*256+col+1]; }
    const float bA = b3[col], bB = b3[col+1];
#pragma unroll 1
    for (int lr=0;lr<8;lr+=2){
      const int gr0 = rg*8+lr, gr1 = gr0+1;
      float a0=bA,a1=bB,a2=bA,a3=bB;
      const float4* zu = (const float4*)&zstage[gr0*36];
      const float4* zv = (const float4*)&zstage[gr1*36];
#pragma unroll
      for (int j=0;j<8;++j){ float4 u=zu[j], v=zv[j]; FMA_CHUNK(u,v,4*j,wzA,wzB) }
      *(float2*)&zw3[gr0*256+col] = make_float2(a0,a1);
      *(float2*)&zw3[gr1*256+col] = make_float2(a2,a3);
    }
  }
  const int gls = lane>>5, gch = gp*32 + (lane&31);
  float c_[4] = {0.f,0.f,0.f,0.f};
  __syncthreads();

#pragma unroll 1
  for (int t=0;t<=TT;++t){
    if (t < TT){
#pragma unroll 1
      for (int lr=0;lr<8;lr+=2){
        const int gr0 = rg*8+lr, gr1 = gr0+1;
        const float2 i0 = *(const float2*)&zw3[gr0*256+col];
        const float2 i1 = *(const float2*)&zw3[gr1*256+col];
        float a0=i0.x, a1=i0.y, a2=i1.x, a3=i1.y;
        const float4* hu = (const float4*)&hs[gr0*HS];
        const float4* hv = (const float4*)&hs[gr1*HS];
#pragma unroll
        for (int j=0;j<16;++j){ float4 u=hu[j], v=hv[j]; FMA_CHUNK(u,v,4*j,wA,wB) }
        *(float2*)&zs[rg][(g*8+lr  )*ZS+chA] = make_float2(a0,a1);
        *(float2*)&zs[rg][(g*8+lr+1)*ZS+chA] = make_float2(a2,a3);
      }
    }
    if (t > 0){
      const int tw = t-1;
#pragma unroll 1
      for (int lr=0;lr<8;++lr){
        const int r = rg*8+lr;
        const float4* hp = (const float4*)&hs[r*HS];
        float d = 0.f;
#pragma unroll
        for (int j=0;j<4;++j){
          float4 u = hp[kq*4+j];
          d = fmaf(u.x, wd[4*j+0], d);
          d = fmaf(u.y, wd[4*j+1], d);
          d = fmaf(u.z, wd[4*j+2], d);
          d = fmaf(u.w, wd[4*j+3], d);
        }
        d += __shfl_xor(d,1);
        d += __shfl_xor(d,2);
        if (dactive && kq==0)
          out[((size_t)(b0+r)*TT + tw)*FF + dcol] = d + bdv;
      }
    }
    __syncthreads();
    if (t < TT){
#pragma unroll
      for (int it=0; it<4; ++it){
        const int lr = 2*it + gls;
        const float zi = zs[rg][(0*8+lr)*ZS+gch];
        const float zf = zs[rg][(1*8+lr)*ZS+gch];
        const float zg = zs[rg][(2*8+lr)*ZS+gch];
        const float zo = zs[rg][(3*8+lr)*ZS+gch];
        const float ig=sigf(zi), fg=sigf(zf), gg=fmaxf(zg,0.f), og=sigf(zo);
        const float cn = fg*c_[it] + ig*gg;
        c_[it]=cn;
        hs[(rg*8+lr)*HS + gch] = og*fmaxf(cn,0.f);
      }
    }
    __syncthreads();
  }
}

extern "C" void kernel_launch(void* const* d_in, const int* in_sizes, int n_in,
                              void* d_out, int out_size, void* d_ws, size_t ws_size,
                              hipStream_t stream){
  const float* x  = (const float*)d_in[0];
  const float* W1 = (const float*)d_in[1];
  const float* U1 = (const float*)d_in[2];
  const float* b1 = (const float*)d_in[3];
  const float* W2 = (const float*)d_in[4];
  const float* U2 = (const float*)d_in[5];
  const float* b2 = (const float*)d_in[6];
  const float* W3 = (const float*)d_in[7];
  const float* U3 = (const float*)d_in[8];
  const float* b3 = (const float*)d_in[9];
  const float* Wd = (const float*)d_in[10];
  const float* bd = (const float*)d_in[11];
  float* out = (float*)d_out;
  float* h1seq = (float*)d_ws;                      // [T][B][64] = 104.9 MB
  float* zlat  = h1seq + (size_t)TT*BB*64;          // [B][32]    = 1.0 MB

  hipLaunchKernelGGL(lstm1_k, dim3(256), dim3(512), 0, stream, x, W1, U1, b1, h1seq);
  hipLaunchKernelGGL(lstm2_k, dim3(256), dim3(512), 0, stream, h1seq, W2, U2, b2, zlat);
  hipLaunchKernelGGL(lstm3_k, dim3(256), dim3(512), 0, stream, zlat, W3, U3, b3, Wd, bd, out);
}

// Round 3
// 991.927 us; speedup vs baseline: 6.5387x; 4.9384x over previous
//
#include <hip/hip_runtime.h>
#include <cstdint>

#define BB 8192
#define TT 50
#define FF 24

__device__ __forceinline__ float sigf(float x){ return 1.0f/(1.0f + __expf(-x)); }

// 4 fp32 FMA chunks: 2 cols (WA,WB) x 2 rows (u,v) -> 4 independent acc chains
#define FMA_CHUNK(u,v,kb,WA,WB) \
  a0 = fmaf((u).x, WA[(kb)+0], a0); a1 = fmaf((u).x, WB[(kb)+0], a1); \
  a2 = fmaf((v).x, WA[(kb)+0], a2); a3 = fmaf((v).x, WB[(kb)+0], a3); \
  a0 = fmaf((u).y, WA[(kb)+1], a0); a1 = fmaf((u).y, WB[(kb)+1], a1); \
  a2 = fmaf((v).y, WA[(kb)+1], a2); a3 = fmaf((v).y, WB[(kb)+1], a3); \
  a0 = fmaf((u).z, WA[(kb)+2], a0); a1 = fmaf((u).z, WB[(kb)+2], a1); \
  a2 = fmaf((v).z, WA[(kb)+2], a2); a3 = fmaf((v).z, WB[(kb)+2], a3); \
  a0 = fmaf((u).w, WA[(kb)+3], a0); a1 = fmaf((u).w, WB[(kb)+3], a1); \
  a2 = fmaf((v).w, WA[(kb)+3], a2); a3 = fmaf((v).w, WB[(kb)+3], a3);

// K-split layout: lane-half kh (lane>>5) owns the 16B k-chunks with index
// 2*j+kh. Partial sums combined with __shfl_xor(.,32). This halves per-lane
// weight residency (the round-2 spill killer) while keeping 8 FMA per
// ds_read_b128. All kernels target <=128 VGPRs (the allocator's hard cap
// here -- launch_bounds could not raise it, rounds 1-2).

// ---------------- LSTM1: x[B][T][24] -> h1seq[T][B][64] ----------------
// 512 blocks x 512 thr; 16 rows/block. waves = gate(4) x row-half(2).
// lane: kh = k-half, li -> col pair g*64+2*li. K = 24(x)+64(h) = 88.
__global__ __launch_bounds__(512) void lstm1_k(
    const float* __restrict__ x, const float* __restrict__ W1,
    const float* __restrict__ U1, const float* __restrict__ b1,
    float* __restrict__ h1seq)
{
  constexpr int R = 16, KS = 96, ZS = 264;
  __shared__ __align__(16) float ks[R*KS];   // [x(24) | h(64) | pad]
  __shared__ __align__(16) float zs[R*ZS];
  __shared__ float bs[256];

  const int tid = threadIdx.x;
  const int wave = tid>>6, lane = tid&63;
  const int g = wave>>1, rh = wave&1;
  const int kh = lane>>5, li = lane&31;
  const int col = g*64 + 2*li;
  const int b0 = blockIdx.x*R;

  float wA[44], wB[44];
#pragma unroll
  for (int j=0;j<11;++j){
#pragma unroll
    for (int e=0;e<4;++e){
      int k = 4*(2*j+kh)+e;                      // 0..87 over both halves
      wA[4*j+e] = (k<24) ? W1[k*256+col]   : U1[(k-24)*256+col];
      wB[4*j+e] = (k<24) ? W1[k*256+col+1] : U1[(k-24)*256+col+1];
    }
  }

  // init: zero h region, stage biases and x_0
  for (int i=tid;i<R*64;i+=512) ks[(i>>6)*KS + 24 + (i&63)] = 0.f;
  if (tid<256) bs[tid] = b1[tid];
  if (tid<R*FF){ int r=tid/FF, f=tid-r*FF; ks[r*KS+f] = x[((size_t)(b0+r)*TT+0)*FF+f]; }

  float c_[2] = {0.f,0.f};
  __syncthreads();

#pragma unroll 1
  for (int t=0;t<TT;++t){
    // dot: z = [x|h] @ [W1;U1]
#pragma unroll 1
    for (int p=0;p<4;++p){
      const int r0 = rh*8 + 2*p, r1 = r0+1;
      const float4* kp0 = (const float4*)&ks[r0*KS];
      const float4* kp1 = (const float4*)&ks[r1*KS];
      float a0=0.f,a1=0.f,a2=0.f,a3=0.f;
#pragma unroll
      for (int j=0;j<11;++j){ float4 u=kp0[2*j+kh], v=kp1[2*j+kh]; FMA_CHUNK(u,v,4*j,wA,wB) }
      a0 += __shfl_xor(a0,32); a1 += __shfl_xor(a1,32);
      a2 += __shfl_xor(a2,32); a3 += __shfl_xor(a3,32);
      if (kh==0){
        *(float2*)&zs[r0*ZS+col] = make_float2(a0,a1);
        *(float2*)&zs[r1*ZS+col] = make_float2(a2,a3);
      }
    }
    __syncthreads();
    // gate math + h write + stage x_{t+1}
#pragma unroll
    for (int it=0; it<2; ++it){
      const int idx = tid + 512*it;
      const int row = idx>>6, ch = idx&63;
      const float zi = zs[row*ZS +       ch] + bs[      ch];
      const float zf = zs[row*ZS +  64 + ch] + bs[ 64 + ch];
      const float zg = zs[row*ZS + 128 + ch] + bs[128 + ch];
      const float zo = zs[row*ZS + 192 + ch] + bs[192 + ch];
      const float ig=sigf(zi), fg=sigf(zf), gg=fmaxf(zg,0.f), og=sigf(zo);
      const float cn = fg*c_[it] + ig*gg;
      c_[it]=cn;
      const float hn = og*fmaxf(cn,0.f);
      ks[row*KS+24+ch] = hn;
      h1seq[(size_t)t*BB*64 + (size_t)(b0+row)*64 + ch] = hn;
    }
    if (t+1<TT && tid<R*FF){
      int r=tid/FF, f=tid-r*FF;
      ks[r*KS+f] = x[((size_t)(b0+r)*TT+(t+1))*FF+f];
    }
    __syncthreads();
  }
}

// ---------------- LSTM2: h1seq[T][B][64] -> zlat[B][32] ----------------
// 512 blocks x 512 thr; 16 rows/block. waves = col-group(2) x row-quarter(4).
// K = 64(h1)+32(h2) = 96; kh split -> 48 k/lane, 2 cols -> 96 weight regs.
__global__ __launch_bounds__(512) void lstm2_k(
    const float* __restrict__ h1seq, const float* __restrict__ W2,
    const float* __restrict__ U2, const float* __restrict__ b2,
    float* __restrict__ zlat)
{
  constexpr int R = 16, KS = 96, ZS = 136;
  __shared__ __align__(16) float ks[R*KS];   // [h1(64) | h2(32)]
  __shared__ __align__(16) float zs[R*ZS];
  __shared__ float bs[128];

  const int tid = threadIdx.x, wave = tid>>6, lane = tid&63;
  const int cg = wave>>2, rw = wave&3;
  const int kh = lane>>5, li = lane&31;
  const int col = cg*64 + 2*li;
  const int b0 = blockIdx.x*R;

  float wA[48], wB[48];
#pragma unroll
  for (int j=0;j<12;++j){
#pragma unroll
    for (int e=0;e<4;++e){
      int k = 4*(2*j+kh)+e;                      // 0..95
      wA[4*j+e] = (k<64) ? W2[k*128+col]   : U2[(k-64)*128+col];
      wB[4*j+e] = (k<64) ? W2[k*128+col+1] : U2[(k-64)*128+col+1];
    }
  }

  for (int i=tid;i<R*32;i+=512) ks[(i>>5)*KS + 64 + (i&31)] = 0.f;
  if (tid<128) bs[tid] = b2[tid];
  for (int i=tid;i<R*64;i+=512) ks[(i>>6)*KS + (i&63)] = h1seq[(size_t)b0*64 + i];

  float c_ = 0.f;
  __syncthreads();

#pragma unroll 1
  for (int t=0;t<TT;++t){
#pragma unroll 1
    for (int p=0;p<2;++p){
      const int r0 = rw*4 + 2*p, r1 = r0+1;
      const float4* kp0 = (const float4*)&ks[r0*KS];
      const float4* kp1 = (const float4*)&ks[r1*KS];
      float a0=0.f,a1=0.f,a2=0.f,a3=0.f;
#pragma unroll
      for (int j=0;j<12;++j){ float4 u=kp0[2*j+kh], v=kp1[2*j+kh]; FMA_CHUNK(u,v,4*j,wA,wB) }
      a0 += __shfl_xor(a0,32); a1 += __shfl_xor(a1,32);
      a2 += __shfl_xor(a2,32); a3 += __shfl_xor(a3,32);
      if (kh==0){
        *(float2*)&zs[r0*ZS+col] = make_float2(a0,a1);
        *(float2*)&zs[r1*ZS+col] = make_float2(a2,a3);
      }
    }
    __syncthreads();
    {
      const int row = tid>>5, ch = tid&31;
      const float zi = zs[row*ZS +      ch] + bs[     ch];
      const float zf = zs[row*ZS + 32 + ch] + bs[32 + ch];
      const float zg = zs[row*ZS + 64 + ch] + bs[64 + ch];
      const float zo = zs[row*ZS + 96 + ch] + bs[96 + ch];
      const float ig=sigf(zi), fg=sigf(zf), gg=fmaxf(zg,0.f), og=sigf(zo);
      const float cn = fg*c_ + ig*gg;
      c_ = cn;
      const float hn = og*fmaxf(cn,0.f);
      ks[row*KS+64+ch] = hn;
      if (t==TT-1) zlat[(size_t)(b0+row)*32+ch] = hn;
    }
    if (t+1<TT){
      for (int i=tid;i<R*64;i+=512)
        ks[(i>>6)*KS + (i&63)] = h1seq[(size_t)(t+1)*BB*64 + (size_t)b0*64 + i];
    }
    __syncthreads();
  }
}

// ---------- LSTM3 + fused Dense: zlat[B][32] -> out[B][T][24] ----------
// z@W3+b3 precomputed once into LDS (RepeatVector invariant). t-loop: h@U3
// (K=64, kh split -> 64 weight regs). Dense reads h_{t-1} + Wd from LDS,
// pipelined one step behind the recurrence.
__global__ __launch_bounds__(512) void lstm3_k(
    const float* __restrict__ zlat, const float* __restrict__ W3,
    const float* __restrict__ U3, const float* __restrict__ b3,
    const float* __restrict__ Wd, const float* __restrict__ bd,
    float* __restrict__ out)
{
  constexpr int R=16, HSK=72, ZS=264;
  __shared__ __align__(16) float ks[R*HSK];   // h(64) | pad
  __shared__ __align__(16) float zw3[R*ZS];   // b3 + z@W3 (invariant)
  __shared__ __align__(16) float zs[R*ZS];
  __shared__ __align__(16) float zst[R*36];   // staged z
  __shared__ __align__(16) float wdl[24*68];  // Wd^T, padded

  const int tid=threadIdx.x, wave=tid>>6, lane=tid&63;
  const int g=wave>>1, rh=wave&1;
  const int kh=lane>>5, li=lane&31;
  const int col=g*64+2*li;
  const int b0=blockIdx.x*R;

  float wA[32], wB[32];
#pragma unroll
  for (int j=0;j<8;++j){
#pragma unroll
    for (int e=0;e<4;++e){
      int k=4*(2*j+kh)+e;                        // 0..63
      wA[4*j+e]=U3[k*256+col]; wB[4*j+e]=U3[k*256+col+1];
    }
  }

  // dense role: kq = k-half(32), dc0 = out col (lanes with dc0<24 active)
  const int kq = lane&1, dc0 = lane>>1;
  const int dact = (dc0<24);
  const int dc = dact? dc0 : 0;
  const float bdv = bd[dc];

  for (int i=tid;i<R*HSK;i+=512) ks[i]=0.f;
  { int r=tid>>5, k2=tid&31; zst[r*36+k2]=zlat[(size_t)b0*32+tid]; }
  for (int i=tid;i<24*64;i+=512){ int c=i>>6,k=i&63; wdl[c*68+k]=Wd[k*24+c]; }
  __syncthreads();

  // zw3 = b3 + z @ W3 (once; K=32 kh-split 16/16)
  {
    float zA[16], zB[16];
#pragma unroll
    for (int j=0;j<4;++j){
#pragma unroll
      for (int e=0;e<4;++e){
        int k=4*(2*j+kh)+e;                      // 0..31
        zA[4*j+e]=W3[k*256+col]; zB[4*j+e]=W3[k*256+col+1];
      }
    }
    const float bA=b3[col], bB=b3[col+1];
#pragma unroll 1
    for (int p=0;p<4;++p){
      const int r0=rh*8+2*p, r1=r0+1;
      const float4* kp0=(const float4*)&zst[r0*36];
      const float4* kp1=(const float4*)&zst[r1*36];
      float a0=0.f,a1=0.f,a2=0.f,a3=0.f;
#pragma unroll
      for (int j=0;j<4;++j){ float4 u=kp0[2*j+kh], v=kp1[2*j+kh]; FMA_CHUNK(u,v,4*j,zA,zB) }
      a0+=__shfl_xor(a0,32); a1+=__shfl_xor(a1,32);
      a2+=__shfl_xor(a2,32); a3+=__shfl_xor(a3,32);
      if (kh==0){
        *(float2*)&zw3[r0*ZS+col]=make_float2(a0+bA,a1+bB);
        *(float2*)&zw3[r1*ZS+col]=make_float2(a2+bA,a3+bB);
      }
    }
  }
  float c_[2]={0.f,0.f};
  __syncthreads();

#pragma unroll 1
  for (int t=0;t<TT;++t){
    // dot: z = zw3 + h_{t-1} @ U3
#pragma unroll 1
    for (int p=0;p<4;++p){
      const int r0=rh*8+2*p, r1=r0+1;
      float a0,a1,a2,a3;
      if (kh==0){
        float2 i0=*(const float2*)&zw3[r0*ZS+col];
        float2 i1=*(const float2*)&zw3[r1*ZS+col];
        a0=i0.x;a1=i0.y;a2=i1.x;a3=i1.y;
      } else { a0=0.f;a1=0.f;a2=0.f;a3=0.f; }
      const float4* kp0=(const float4*)&ks[r0*HSK];
      const float4* kp1=(const float4*)&ks[r1*HSK];
#pragma unroll
      for (int j=0;j<8;++j){ float4 u=kp0[2*j+kh], v=kp1[2*j+kh]; FMA_CHUNK(u,v,4*j,wA,wB) }
      a0+=__shfl_xor(a0,32); a1+=__shfl_xor(a1,32);
      a2+=__shfl_xor(a2,32); a3+=__shfl_xor(a3,32);
      if (kh==0){
        *(float2*)&zs[r0*ZS+col]=make_float2(a0,a1);
        *(float2*)&zs[r1*ZS+col]=make_float2(a2,a3);
      }
    }
    // dense(t-1): out[., t-1, .] = h_{t-1} @ Wd + bd  (reads same ks as dot)
    if (t>0){
      const int tw=t-1;
#pragma unroll
      for (int rr=0;rr<2;++rr){
        const int row=2*wave+rr;
        const float4* hp=(const float4*)&ks[row*HSK + kq*32];
        const float4* wp=(const float4*)&wdl[dc*68 + kq*32];
        float d=0.f;
#pragma unroll
        for (int j=0;j<8;++j){
          float4 u=hp[j], w=wp[j];
          d=fmaf(u.x,w.x,d); d=fmaf(u.y,w.y,d); d=fmaf(u.z,w.z,d); d=fmaf(u.w,w.w,d);
        }
        d+=__shfl_xor(d,1);
        if (dact && kq==0) out[((size_t)(b0+row)*TT+tw)*FF+dc0]=d+bdv;
      }
    }
    __syncthreads();
    // gate math (zw3 already holds bias)
#pragma unroll
    for (int it=0;it<2;++it){
      const int idx=tid+512*it, row=idx>>6, ch=idx&63;
      const float zi=zs[row*ZS+      ch];
      const float zf=zs[row*ZS+ 64 + ch];
      const float zg=zs[row*ZS+128 + ch];
      const float zo=zs[row*ZS+192 + ch];
      const float ig=sigf(zi), fg=sigf(zf), gg=fmaxf(zg,0.f), og=sigf(zo);
      const float cn = fg*c_[it] + ig*gg;
      c_[it]=cn;
      ks[row*HSK+ch] = og*fmaxf(cn,0.f);
    }
    __syncthreads();
  }
  // dense for t = TT-1
  {
    const int tw=TT-1;
#pragma unroll
    for (int rr=0;rr<2;++rr){
      const int row=2*wave+rr;
      const float4* hp=(const float4*)&ks[row*HSK + kq*32];
      const float4* wp=(const float4*)&wdl[dc*68 + kq*32];
      float d=0.f;
#pragma unroll
      for (int j=0;j<8;++j){
        float4 u=hp[j], w=wp[j];
        d=fmaf(u.x,w.x,d); d=fmaf(u.y,w.y,d); d=fmaf(u.z,w.z,d); d=fmaf(u.w,w.w,d);
      }
      d+=__shfl_xor(d,1);
      if (dact && kq==0) out[((size_t)(b0+row)*TT+tw)*FF+dc0]=d+bdv;
    }
  }
}

extern "C" void kernel_launch(void* const* d_in, const int* in_sizes, int n_in,
                              void* d_out, int out_size, void* d_ws, size_t ws_size,
                              hipStream_t stream){
  const float* x  = (const float*)d_in[0];
  const float* W1 = (const float*)d_in[1];
  const float* U1 = (const float*)d_in[2];
  const float* b1 = (const float*)d_in[3];
  const float* W2 = (const float*)d_in[4];
  const float* U2 = (const float*)d_in[5];
  const float* b2 = (const float*)d_in[6];
  const float* W3 = (const float*)d_in[7];
  const float* U3 = (const float*)d_in[8];
  const float* b3 = (const float*)d_in[9];
  const float* Wd = (const float*)d_in[10];
  const float* bd = (const float*)d_in[11];
  float* out = (float*)d_out;
  float* h1seq = (float*)d_ws;                      // [T][B][64] = 104.9 MB
  float* zlat  = h1seq + (size_t)TT*BB*64;          // [B][32]    = 1.0 MB

  hipLaunchKernelGGL(lstm1_k, dim3(512), dim3(512), 0, stream, x, W1, U1, b1, h1seq);
  hipLaunchKernelGGL(lstm2_k, dim3(512), dim3(512), 0, stream, h1seq, W2, U2, b2, zlat);
  hipLaunchKernelGGL(lstm3_k, dim3(512), dim3(512), 0, stream, zlat, W3, U3, b3, Wd, bd, out);
}

// Round 4
// 379.148 us; speedup vs baseline: 17.1065x; 2.6162x over previous
//
#include <hip/hip_runtime.h>
#include <cstdint>

#define BB 8192
#define TT 50
#define FF 24

typedef __attribute__((ext_vector_type(8))) short short8;
typedef __attribute__((ext_vector_type(4))) float f32x4;

__device__ __forceinline__ float sigf(float x){ return 1.0f/(1.0f + __expf(-x)); }

// Exact 3-way bf16 split (truncation / Dekker): w == s1 + s2 + s3 to 24 bits.
__device__ __forceinline__ void split3(float w, unsigned short& s1,
                                       unsigned short& s2, unsigned short& s3){
  unsigned b1 = __float_as_uint(w);
  s1 = (unsigned short)(b1 >> 16);
  float r = w - __uint_as_float(b1 & 0xFFFF0000u);       // exact
  unsigned b2 = __float_as_uint(r);
  s2 = (unsigned short)(b2 >> 16);
  float r2 = r - __uint_as_float(b2 & 0xFFFF0000u);      // exact
  s3 = (unsigned short)(__float_as_uint(r2) >> 16);
}

#define MFMA(A,B,C) __builtin_amdgcn_mfma_f32_16x16x32_bf16((A),(B),(C),0,0,0)

// 6-product bf16x3 accumulation for one (A-set, B-set) pair into C
#define PROD6(C,A1,A2,A3,Bq1,Bq2,Bq3) \
  C = MFMA(A1,Bq1,C); C = MFMA(A1,Bq2,C); C = MFMA(A2,Bq1,C); \
  C = MFMA(A2,Bq2,C); C = MFMA(A1,Bq3,C); C = MFMA(A3,Bq1,C);

// fp32 FMA chunk for the lstm3 zw3 prologue (vector path)
#define FMA_CHUNK(u,v,kb,WA,WB) \
  a0 = fmaf((u).x, WA[(kb)+0], a0); a1 = fmaf((u).x, WB[(kb)+0], a1); \
  a2 = fmaf((v).x, WA[(kb)+0], a2); a3 = fmaf((v).x, WB[(kb)+0], a3); \
  a0 = fmaf((u).y, WA[(kb)+1], a0); a1 = fmaf((u).y, WB[(kb)+1], a1); \
  a2 = fmaf((v).y, WA[(kb)+1], a2); a3 = fmaf((v).y, WB[(kb)+1], a3); \
  a0 = fmaf((u).z, WA[(kb)+2], a0); a1 = fmaf((u).z, WB[(kb)+2], a1); \
  a2 = fmaf((v).z, WA[(kb)+2], a2); a3 = fmaf((v).z, WB[(kb)+2], a3); \
  a0 = fmaf((u).w, WA[(kb)+3], a0); a1 = fmaf((u).w, WB[(kb)+3], a1); \
  a2 = fmaf((v).w, WA[(kb)+3], a2); a3 = fmaf((v).w, WB[(kb)+3], a3);

// MFMA layouts (gfx950 16x16x32, HW-verified m89/m120):
//  A[m = lane&15][k = (lane>>4)*8 + j]   (8 bf16 = short8)
//  B[k = (lane>>4)*8 + j][n = lane&15]
//  C: col = lane&15, row = (lane>>4)*4 + reg
// A-split LDS stride 104 ushorts (208 B): 16B-aligned rows, bank-spread.

// ---------------- LSTM1: x[B][T][24] -> h1seq[T][B][64] ----------------
// 512 blocks x 512 thr, 16 rows/block. A = [x_t(24) | h_{t-1}(64) | pad(8)],
// K=96 (3 ksteps). N=256: 8 waves x 2 ntiles. B resident: 18 frags = 72 VGPR.
__global__ __launch_bounds__(512) void lstm1_k(
    const float* __restrict__ x, const float* __restrict__ W1,
    const float* __restrict__ U1, const float* __restrict__ b1,
    float* __restrict__ h1seq)
{
  constexpr int AS = 104, ZS = 260;
  __shared__ __align__(16) unsigned short asp[3][16*AS];
  __shared__ float zs[16*ZS];
  __shared__ float bs[256];

  const int tid = threadIdx.x, wave = tid>>6, lane = tid&63;
  const int quad = lane>>4, li = lane&15;
  const int b0 = blockIdx.x*16;

  // Resident B-fragments (weights, loaded once)
  short8 B1[2][3], B2[2][3], B3[2][3];
#pragma unroll
  for (int nt=0; nt<2; ++nt){
#pragma unroll
    for (int ks=0; ks<3; ++ks){
      short8 v1, v2, v3;
#pragma unroll
      for (int j=0; j<8; ++j){
        const int k = ks*32 + quad*8 + j;
        const int c = wave*32 + nt*16 + li;
        float w = (k<24) ? W1[k*256+c] : ((k<88) ? U1[(k-24)*256+c] : 0.f);
        unsigned short s1,s2,s3; split3(w,s1,s2,s3);
        v1[j]=(short)s1; v2[j]=(short)s2; v3[j]=(short)s3;
      }
      B1[nt][ks]=v1; B2[nt][ks]=v2; B3[nt][ks]=v3;
    }
  }

  for (int i=tid; i<3*16*AS/2; i+=512) ((unsigned int*)asp)[i] = 0u;
  if (tid<256) bs[tid] = b1[tid];
  __syncthreads();
  if (tid < 16*FF){
    int r = tid/FF, f = tid - r*FF;
    unsigned short s1,s2,s3;
    split3(x[((size_t)(b0+r)*TT + 0)*FF + f], s1,s2,s3);
    asp[0][r*AS+f]=s1; asp[1][r*AS+f]=s2; asp[2][r*AS+f]=s3;
  }
  float c_[2] = {0.f, 0.f};
  __syncthreads();

#pragma unroll 1
  for (int t=0; t<TT; ++t){
    f32x4 C0 = {0.f,0.f,0.f,0.f}, C1 = {0.f,0.f,0.f,0.f};
#pragma unroll
    for (int ks=0; ks<3; ++ks){
      const int ab = li*AS + ks*32 + quad*8;
      short8 A1 = *(const short8*)&asp[0][ab];
      short8 A2 = *(const short8*)&asp[1][ab];
      short8 A3 = *(const short8*)&asp[2][ab];
      PROD6(C0, A1,A2,A3, B1[0][ks],B2[0][ks],B3[0][ks])
      PROD6(C1, A1,A2,A3, B1[1][ks],B2[1][ks],B3[1][ks])
    }
#pragma unroll
    for (int i=0;i<4;++i){
      zs[(quad*4+i)*ZS + wave*32 + li]      = C0[i];
      zs[(quad*4+i)*ZS + wave*32 + 16 + li] = C1[i];
    }
    __syncthreads();
#pragma unroll
    for (int it=0; it<2; ++it){
      const int idx = tid + 512*it, row = idx>>6, ch = idx&63;
      const float zi = zs[row*ZS +       ch] + bs[      ch];
      const float zf = zs[row*ZS +  64 + ch] + bs[ 64 + ch];
      const float zg = zs[row*ZS + 128 + ch] + bs[128 + ch];
      const float zo = zs[row*ZS + 192 + ch] + bs[192 + ch];
      const float ig=sigf(zi), fg=sigf(zf), gg=fmaxf(zg,0.f), og=sigf(zo);
      const float cn = fg*c_[it] + ig*gg;
      c_[it] = cn;
      const float hn = og*fmaxf(cn,0.f);
      h1seq[(size_t)t*BB*64 + (size_t)(b0+row)*64 + ch] = hn;
      unsigned short s1,s2,s3; split3(hn,s1,s2,s3);
      asp[0][row*AS+24+ch]=s1; asp[1][row*AS+24+ch]=s2; asp[2][row*AS+24+ch]=s3;
    }
    if (t+1<TT && tid < 16*FF){
      int r = tid/FF, f = tid - r*FF;
      unsigned short s1,s2,s3;
      split3(x[((size_t)(b0+r)*TT + (t+1))*FF + f], s1,s2,s3);
      asp[0][r*AS+f]=s1; asp[1][r*AS+f]=s2; asp[2][r*AS+f]=s3;
    }
    __syncthreads();
  }
}

// ---------------- LSTM2: h1seq[T][B][64] -> zlat[B][32] ----------------
// 512 blocks x 512 thr, 16 rows/block. A = [h1_t(64) | h2_{t-1}(32)], K=96.
// N=128: 8 waves x 1 ntile. B resident: 9 frags = 36 VGPR.
__global__ __launch_bounds__(512) void lstm2_k(
    const float* __restrict__ h1seq, const float* __restrict__ W2,
    const float* __restrict__ U2, const float* __restrict__ b2,
    float* __restrict__ zlat)
{
  constexpr int AS = 104, ZS = 132;
  __shared__ __align__(16) unsigned short asp[3][16*AS];
  __shared__ float zs[16*ZS];
  __shared__ float bs[128];

  const int tid = threadIdx.x, wave = tid>>6, lane = tid&63;
  const int quad = lane>>4, li = lane&15;
  const int b0 = blockIdx.x*16;

  short8 B1[3], B2s[3], B3[3];
#pragma unroll
  for (int ks=0; ks<3; ++ks){
    short8 v1,v2,v3;
#pragma unroll
    for (int j=0; j<8; ++j){
      const int k = ks*32 + quad*8 + j;
      const int c = wave*16 + li;
      float w = (k<64) ? W2[k*128+c] : U2[(k-64)*128+c];
      unsigned short s1,s2,s3; split3(w,s1,s2,s3);
      v1[j]=(short)s1; v2[j]=(short)s2; v3[j]=(short)s3;
    }
    B1[ks]=v1; B2s[ks]=v2; B3[ks]=v3;
  }

  for (int i=tid; i<3*16*AS/2; i+=512) ((unsigned int*)asp)[i] = 0u;
  if (tid<128) bs[tid] = b2[tid];
  __syncthreads();
#pragma unroll
  for (int e=0; e<2; ++e){
    const int idx = tid + 512*e, r = idx>>6, kk = idx&63;
    unsigned short s1,s2,s3;
    split3(h1seq[(size_t)b0*64 + idx], s1,s2,s3);
    asp[0][r*AS+kk]=s1; asp[1][r*AS+kk]=s2; asp[2][r*AS+kk]=s3;
  }
  float c_ = 0.f;
  __syncthreads();

#pragma unroll 1
  for (int t=0; t<TT; ++t){
    f32x4 C0 = {0.f,0.f,0.f,0.f};
#pragma unroll
    for (int ks=0; ks<3; ++ks){
      const int ab = li*AS + ks*32 + quad*8;
      short8 A1 = *(const short8*)&asp[0][ab];
      short8 A2 = *(const short8*)&asp[1][ab];
      short8 A3 = *(const short8*)&asp[2][ab];
      PROD6(C0, A1,A2,A3, B1[ks],B2s[ks],B3[ks])
    }
#pragma unroll
    for (int i=0;i<4;++i) zs[(quad*4+i)*ZS + wave*16 + li] = C0[i];
    __syncthreads();
    {
      const int row = tid>>5, ch = tid&31;
      const float zi = zs[row*ZS +      ch] + bs[     ch];
      const float zf = zs[row*ZS + 32 + ch] + bs[32 + ch];
      const float zg = zs[row*ZS + 64 + ch] + bs[64 + ch];
      const float zo = zs[row*ZS + 96 + ch] + bs[96 + ch];
      const float ig=sigf(zi), fg=sigf(zf), gg=fmaxf(zg,0.f), og=sigf(zo);
      const float cn = fg*c_ + ig*gg;
      c_ = cn;
      const float hn = og*fmaxf(cn,0.f);
      unsigned short s1,s2,s3; split3(hn,s1,s2,s3);
      asp[0][row*AS+64+ch]=s1; asp[1][row*AS+64+ch]=s2; asp[2][row*AS+64+ch]=s3;
      if (t == TT-1) zlat[(size_t)(b0+row)*32 + ch] = hn;
    }
    if (t+1<TT){
#pragma unroll
      for (int e=0; e<2; ++e){
        const int idx = tid + 512*e, r = idx>>6, kk = idx&63;
        unsigned short s1,s2,s3;
        split3(h1seq[(size_t)(t+1)*BB*64 + (size_t)b0*64 + idx], s1,s2,s3);
        asp[0][r*AS+kk]=s1; asp[1][r*AS+kk]=s2; asp[2][r*AS+kk]=s3;
      }
    }
    __syncthreads();
  }
}

// ---------- LSTM3 + fused Dense: zlat[B][32] -> out[B][T][24] ----------
// zw3 = b3 + z@W3 precomputed (fp32 vector, once). t-loop: h@U3 via MFMA
// (K=64, 2 ksteps; N=256: 8 waves x 2 ntiles, B = 12 frags = 48 VGPR).
// Dense fused as MFMA on waves 0/1 (N=24 pad 32, bf16x2), reusing A-frags.
__global__ __launch_bounds__(512) void lstm3_k(
    const float* __restrict__ zlat, const float* __restrict__ W3,
    const float* __restrict__ U3, const float* __restrict__ b3,
    const float* __restrict__ Wd, const float* __restrict__ bd,
    float* __restrict__ out)
{
  constexpr int AS = 104, ZS = 260;
  __shared__ __align__(16) unsigned short asp[3][16*AS];
  __shared__ float zs[16*ZS];
  __shared__ float zw3[16*ZS];
  __shared__ __align__(16) float zst[16*36];

  const int tid = threadIdx.x, wave = tid>>6, lane = tid&63;
  const int quad = lane>>4, li = lane&15;
  const int b0 = blockIdx.x*16;

  // LSTM B-frags (U3)
  short8 B1[2][2], B2[2][2], B3[2][2];
#pragma unroll
  for (int nt=0; nt<2; ++nt){
#pragma unroll
    for (int ks=0; ks<2; ++ks){
      short8 v1,v2,v3;
#pragma unroll
      for (int j=0; j<8; ++j){
        const int k = ks*32 + quad*8 + j;
        const int c = wave*32 + nt*16 + li;
        float w = U3[k*256+c];
        unsigned short s1,s2,s3; split3(w,s1,s2,s3);
        v1[j]=(short)s1; v2[j]=(short)s2; v3[j]=(short)s3;
      }
      B1[nt][ks]=v1; B2[nt][ks]=v2; B3[nt][ks]=v3;
    }
  }
  // Dense B-frags (Wd, bf16x2) on waves 0,1; dense col = wave*16+li
  short8 Bd1[2], Bd2[2];
  const int dcol = wave*16 + li;
  float bdv = 0.f;
  if (wave < 2){
    if (dcol < 24) bdv = bd[dcol];
#pragma unroll
    for (int ks=0; ks<2; ++ks){
      short8 v1,v2;
#pragma unroll
      for (int j=0; j<8; ++j){
        const int k = ks*32 + quad*8 + j;
        float w = (dcol<24) ? Wd[k*24 + dcol] : 0.f;
        unsigned short s1,s2,s3; split3(w,s1,s2,s3);
        v1[j]=(short)s1; v2[j]=(short)s2;
      }
      Bd1[ks]=v1; Bd2[ks]=v2;
    }
  }

  for (int i=tid; i<3*16*AS/2; i+=512) ((unsigned int*)asp)[i] = 0u;
  { int r = tid>>5, kk = tid&31; zst[r*36+kk] = zlat[(size_t)b0*32 + tid]; }
  __syncthreads();

  // zw3 = b3 + z @ W3 (fp32 vector, once; K=32 kh-split as round 3)
  {
    const int g3 = wave>>1, rh3 = wave&1, kh3 = lane>>5, li3 = lane&31;
    const int col3 = g3*64 + 2*li3;
    float zA[16], zB[16];
#pragma unroll
    for (int j=0;j<4;++j){
#pragma unroll
      for (int e=0;e<4;++e){
        int k = 4*(2*j+kh3)+e;
        zA[4*j+e] = W3[k*256+col3]; zB[4*j+e] = W3[k*256+col3+1];
      }
    }
    const float bA = b3[col3], bB = b3[col3+1];
#pragma unroll 1
    for (int p=0;p<4;++p){
      const int r0 = rh3*8 + 2*p, r1 = r0+1;
      const float4* kp0 = (const float4*)&zst[r0*36];
      const float4* kp1 = (const float4*)&zst[r1*36];
      float a0=0.f,a1=0.f,a2=0.f,a3=0.f;
#pragma unroll
      for (int j=0;j<4;++j){ float4 u=kp0[2*j+kh3], v=kp1[2*j+kh3]; FMA_CHUNK(u,v,4*j,zA,zB) }
      a0 += __shfl_xor(a0,32); a1 += __shfl_xor(a1,32);
      a2 += __shfl_xor(a2,32); a3 += __shfl_xor(a3,32);
      if (kh3==0){
        *(float2*)&zw3[r0*ZS+col3] = make_float2(a0+bA, a1+bB);
        *(float2*)&zw3[r1*ZS+col3] = make_float2(a2+bA, a3+bB);
      }
    }
  }
  float c_[2] = {0.f,0.f};
  __syncthreads();

#pragma unroll 1
  for (int t=0; t<=TT; ++t){
    f32x4 C0 = {0.f,0.f,0.f,0.f}, C1 = {0.f,0.f,0.f,0.f};
    f32x4 Cd = {0.f,0.f,0.f,0.f};
#pragma unroll
    for (int ks=0; ks<2; ++ks){
      const int ab = li*AS + ks*32 + quad*8;
      short8 A1 = *(const short8*)&asp[0][ab];
      short8 A2 = *(const short8*)&asp[1][ab];
      short8 A3 = *(const short8*)&asp[2][ab];
      if (t < TT){
        PROD6(C0, A1,A2,A3, B1[0][ks],B2[0][ks],B3[0][ks])
        PROD6(C1, A1,A2,A3, B1[1][ks],B2[1][ks],B3[1][ks])
      }
      if (t > 0 && wave < 2){
        Cd = MFMA(A1,Bd1[ks],Cd); Cd = MFMA(A1,Bd2[ks],Cd); Cd = MFMA(A2,Bd1[ks],Cd);
      }
    }
    if (t < TT){
#pragma unroll
      for (int i=0;i<4;++i){
        zs[(quad*4+i)*ZS + wave*32 + li]      = C0[i];
        zs[(quad*4+i)*ZS + wave*32 + 16 + li] = C1[i];
      }
    }
    if (t > 0 && wave < 2 && dcol < 24){
#pragma unroll
      for (int i=0;i<4;++i){
        const int row = quad*4+i;
        out[((size_t)(b0+row)*TT + (t-1))*FF + dcol] = Cd[i] + bdv;
      }
    }
    __syncthreads();
    if (t < TT){
#pragma unroll
      for (int it=0; it<2; ++it){
        const int idx = tid + 512*it, row = idx>>6, ch = idx&63;
        const float zi = zs[row*ZS +       ch] + zw3[row*ZS +       ch];
        const float zf = zs[row*ZS +  64 + ch] + zw3[row*ZS +  64 + ch];
        const float zg = zs[row*ZS + 128 + ch] + zw3[row*ZS + 128 + ch];
        const float zo = zs[row*ZS + 192 + ch] + zw3[row*ZS + 192 + ch];
        const float ig=sigf(zi), fg=sigf(zf), gg=fmaxf(zg,0.f), og=sigf(zo);
        const float cn = fg*c_[it] + ig*gg;
        c_[it] = cn;
        const float hn = og*fmaxf(cn,0.f);
        unsigned short s1,s2,s3; split3(hn,s1,s2,s3);
        asp[0][row*AS+ch]=s1; asp[1][row*AS+ch]=s2; asp[2][row*AS+ch]=s3;
      }
    }
    __syncthreads();
  }
}

extern "C" void kernel_launch(void* const* d_in, const int* in_sizes, int n_in,
                              void* d_out, int out_size, void* d_ws, size_t ws_size,
                              hipStream_t stream){
  const float* x  = (const float*)d_in[0];
  const float* W1 = (const float*)d_in[1];
  const float* U1 = (const float*)d_in[2];
  const float* b1 = (const float*)d_in[3];
  const float* W2 = (const float*)d_in[4];
  const float* U2 = (const float*)d_in[5];
  const float* b2 = (const float*)d_in[6];
  const float* W3 = (const float*)d_in[7];
  const float* U3 = (const float*)d_in[8];
  const float* b3 = (const float*)d_in[9];
  const float* Wd = (const float*)d_in[10];
  const float* bd = (const float*)d_in[11];
  float* out = (float*)d_out;
  float* h1seq = (float*)d_ws;                      // [T][B][64] = 104.9 MB
  float* zlat  = h1seq + (size_t)TT*BB*64;          // [B][32]    = 1.0 MB

  hipLaunchKernelGGL(lstm1_k, dim3(512), dim3(512), 0, stream, x, W1, U1, b1, h1seq);
  hipLaunchKernelGGL(lstm2_k, dim3(512), dim3(512), 0, stream, h1seq, W2, U2, b2, zlat);
  hipLaunchKernelGGL(lstm3_k, dim3(512), dim3(512), 0, stream, zlat, W3, U3, b3, Wd, bd, out);
}

// Round 5
// 348.768 us; speedup vs baseline: 18.5966x; 1.0871x over previous
//
#include <hip/hip_runtime.h>
#include <cstdint>

#define BB 8192
#define TT 50
#define FF 24

typedef __attribute__((ext_vector_type(8))) short short8;
typedef __attribute__((ext_vector_type(4))) float f32x4;

__device__ __forceinline__ float sigf(float x){ return 1.0f/(1.0f + __expf(-x)); }

// 2-way bf16 split (truncation): w ~= s1 + s2 to ~16 mantissa bits
__device__ __forceinline__ void split2(float w, unsigned short& s1, unsigned short& s2){
  unsigned b = __float_as_uint(w);
  s1 = (unsigned short)(b >> 16);
  float r = w - __uint_as_float(b & 0xFFFF0000u);
  s2 = (unsigned short)(__float_as_uint(r) >> 16);
}

#define MFMA(A,B,C) __builtin_amdgcn_mfma_f32_16x16x32_bf16((A),(B),(C),0,0,0)
// bf16x2, 3 products: error ~2^-16 relative -- sufficient vs 3.83e-5 threshold
#define PROD3(C,A1,A2,Bq1,Bq2) \
  C = MFMA(A1,Bq1,C); C = MFMA(A1,Bq2,C); C = MFMA(A2,Bq1,C);

// fp32 FMA chunk for the zw3 prologue (vector path, once)
#define FMA_CHUNK(u,v,kb,WA,WB) \
  a0 = fmaf((u).x, WA[(kb)+0], a0); a1 = fmaf((u).x, WB[(kb)+0], a1); \
  a2 = fmaf((v).x, WA[(kb)+0], a2); a3 = fmaf((v).x, WB[(kb)+0], a3); \
  a0 = fmaf((u).y, WA[(kb)+1], a0); a1 = fmaf((u).y, WB[(kb)+1], a1); \
  a2 = fmaf((v).y, WA[(kb)+1], a2); a3 = fmaf((v).y, WB[(kb)+1], a3); \
  a0 = fmaf((u).z, WA[(kb)+2], a0); a1 = fmaf((u).z, WB[(kb)+2], a1); \
  a2 = fmaf((v).z, WA[(kb)+2], a2); a3 = fmaf((v).z, WB[(kb)+2], a3); \
  a0 = fmaf((u).w, WA[(kb)+3], a0); a1 = fmaf((u).w, WB[(kb)+3], a1); \
  a2 = fmaf((v).w, WA[(kb)+3], a2); a3 = fmaf((v).w, WB[(kb)+3], a3);

// Fully-fused autoencoder: 512 blocks x 512 thr, 16 batch rows per block.
// The block owns its 16 rows through all 3 LSTMs + dense -- NO HBM
// intermediates (h1seq/zlat eliminated). Phase A: t-loop {MFMA1, gate1,
// MFMA2, gate2} (3 barriers/t). Phase B: zw3 = b3 + z@W3 (fp32, once).
// Phase C: t-loop {MFMA3+dense, gate3} (2 barriers/t).
// MFMA layouts (verified m89): A[m=lane&15][k=quad*8+j], B[k][n=lane&15],
// C: col=lane&15, row=quad*4+reg. Biases folded into MFMA C-init.
__global__ __launch_bounds__(512) void ae_k(
    const float* __restrict__ x,
    const float* __restrict__ W1, const float* __restrict__ U1, const float* __restrict__ b1,
    const float* __restrict__ W2, const float* __restrict__ U2, const float* __restrict__ b2,
    const float* __restrict__ W3, const float* __restrict__ U3, const float* __restrict__ b3,
    const float* __restrict__ Wd, const float* __restrict__ bd,
    float* __restrict__ out)
{
  constexpr int AS1 = 104, AS2 = 40, AS3 = 72, ZS1 = 260, ZS2 = 132;
  __shared__ __align__(16) unsigned short asp1[2][16*AS1]; // [x(24)|h1(64)|pad]
  __shared__ __align__(16) unsigned short asp2[2][16*AS2]; // [h2(32)|pad]
  __shared__ __align__(16) unsigned short asp3[2][16*AS3]; // [h3(64)|pad]
  __shared__ __align__(16) float zs1[16*ZS1];
  __shared__ __align__(16) float zs2[16*ZS2];
  __shared__ __align__(16) float zw3[16*ZS1];
  __shared__ __align__(16) float zst[16*36];

  const int tid = threadIdx.x, wave = tid>>6, lane = tid&63;
  const int quad = lane>>4, li = lane&15;
  const int b0 = blockIdx.x*16;

  // ---- Phase-A resident B-fragments ----
  // L1: N=256 (8 waves x 2 ntiles), K=96 (24 x + 64 h1 + 8 zero-pad)
  short8 B1a[2][3], B1b[2][3];
#pragma unroll
  for (int nt=0; nt<2; ++nt)
#pragma unroll
  for (int ks=0; ks<3; ++ks){
    short8 v1, v2;
#pragma unroll
    for (int j=0; j<8; ++j){
      const int k = ks*32 + quad*8 + j;
      const int c = wave*32 + nt*16 + li;
      float w = (k<24) ? W1[k*256+c] : ((k<88) ? U1[(k-24)*256+c] : 0.f);
      unsigned short s1,s2; split2(w,s1,s2);
      v1[j]=(short)s1; v2[j]=(short)s2;
    }
    B1a[nt][ks]=v1; B1b[nt][ks]=v2;
  }
  // L2: N=128 (8 waves x 1 ntile), K=96 (64 h1 + 32 h2)
  short8 B2a[3], B2b[3];
#pragma unroll
  for (int ks=0; ks<3; ++ks){
    short8 v1, v2;
#pragma unroll
    for (int j=0; j<8; ++j){
      const int k = ks*32 + quad*8 + j;
      const int c = wave*16 + li;
      float w = (k<64) ? W2[k*128+c] : U2[(k-64)*128+c];
      unsigned short s1,s2; split2(w,s1,s2);
      v1[j]=(short)s1; v2[j]=(short)s2;
    }
    B2a[ks]=v1; B2b[ks]=v2;
  }
  const float bi1A = b1[wave*32+li], bi1B = b1[wave*32+16+li];
  const float bi2  = b2[wave*16+li];

  // zero all split planes (covers h1/h2/h3 zero-init + pads)
  for (int i=tid; i<16*AS1; i+=512) ((unsigned int*)asp1)[i] = 0u;
  for (int i=tid; i<16*AS2; i+=512) ((unsigned int*)asp2)[i] = 0u;
  for (int i=tid; i<16*AS3; i+=512) ((unsigned int*)asp3)[i] = 0u;
  __syncthreads();
  if (tid < 16*FF){
    int r = tid/FF, f = tid - r*FF;
    unsigned short s1,s2; split2(x[((size_t)(b0+r)*TT + 0)*FF + f], s1,s2);
    asp1[0][r*AS1+f]=s1; asp1[1][r*AS1+f]=s2;
  }
  float c1_[2] = {0.f,0.f}, c2_[2] = {0.f,0.f};
  __syncthreads();

  // =================== Phase A: L1 + L2 fused t-loop ===================
#pragma unroll 1
  for (int t=0; t<TT; ++t){
    // --- MFMA1: z1 = b1 + [x_t | h1_{t-1}] @ [W1;U1] ---
    f32x4 C0 = {bi1A,bi1A,bi1A,bi1A}, C1v = {bi1B,bi1B,bi1B,bi1B};
#pragma unroll
    for (int ks=0; ks<3; ++ks){
      const int ab = li*AS1 + ks*32 + quad*8;
      short8 A1 = *(const short8*)&asp1[0][ab];
      short8 A2 = *(const short8*)&asp1[1][ab];
      PROD3(C0,  A1,A2, B1a[0][ks],B1b[0][ks])
      PROD3(C1v, A1,A2, B1a[1][ks],B1b[1][ks])
    }
#pragma unroll
    for (int i2=0; i2<4; ++i2){
      zs1[(quad*4+i2)*ZS1 + wave*32 + li]      = C0[i2];
      zs1[(quad*4+i2)*ZS1 + wave*32 + 16 + li] = C1v[i2];
    }
    __syncthreads();                                   // A
    // --- gate1: 512 thr, (row, chan-pair); h1 -> asp1 splits ---
    {
      const int row = tid>>5, chp = tid&31, c0 = 2*chp;
      float xa = 0.f; int xr=0, xf=0;
      const bool doX = (t+1<TT) && (tid < 16*FF);
      if (doX){ xr = tid/FF; xf = tid - xr*FF;
                xa = x[((size_t)(b0+xr)*TT + (t+1))*FF + xf]; }
      float2 zi = *(float2*)&zs1[row*ZS1 +       c0];
      float2 zf = *(float2*)&zs1[row*ZS1 +  64 + c0];
      float2 zg = *(float2*)&zs1[row*ZS1 + 128 + c0];
      float2 zo = *(float2*)&zs1[row*ZS1 + 192 + c0];
      float h0, h1v;
      { float ig=sigf(zi.x), fg=sigf(zf.x), gg=fmaxf(zg.x,0.f), og=sigf(zo.x);
        float cn=fg*c1_[0]+ig*gg; c1_[0]=cn; h0=og*fmaxf(cn,0.f); }
      { float ig=sigf(zi.y), fg=sigf(zf.y), gg=fmaxf(zg.y,0.f), og=sigf(zo.y);
        float cn=fg*c1_[1]+ig*gg; c1_[1]=cn; h1v=og*fmaxf(cn,0.f); }
      unsigned ba=__float_as_uint(h0), bb=__float_as_uint(h1v);
      unsigned p0 = (ba>>16) | (bb & 0xFFFF0000u);
      float ra = h0  - __uint_as_float(ba & 0xFFFF0000u);
      float rb = h1v - __uint_as_float(bb & 0xFFFF0000u);
      unsigned p1 = (__float_as_uint(ra)>>16) | (__float_as_uint(rb) & 0xFFFF0000u);
      *(unsigned*)&asp1[0][row*AS1 + 24 + c0] = p0;
      *(unsigned*)&asp1[1][row*AS1 + 24 + c0] = p1;
      if (doX){
        unsigned short s1,s2; split2(xa,s1,s2);
        asp1[0][xr*AS1+xf]=s1; asp1[1][xr*AS1+xf]=s2;  // x region: MFMA1(t) done
      }
    }
    __syncthreads();                                   // B
    // --- MFMA2: z2 = b2 + [h1_t | h2_{t-1}] @ [W2;U2] ---
    f32x4 C2 = {bi2,bi2,bi2,bi2};
#pragma unroll
    for (int ks=0; ks<2; ++ks){
      const int ab = li*AS1 + 24 + ks*32 + quad*8;     // h1 from asp1
      short8 A1 = *(const short8*)&asp1[0][ab];
      short8 A2 = *(const short8*)&asp1[1][ab];
      PROD3(C2, A1,A2, B2a[ks],B2b[ks])
    }
    {
      const int ab = li*AS2 + quad*8;                  // h2 from asp2
      short8 A1 = *(const short8*)&asp2[0][ab];
      short8 A2 = *(const short8*)&asp2[1][ab];
      PROD3(C2, A1,A2, B2a[2],B2b[2])
    }
#pragma unroll
    for (int i2=0; i2<4; ++i2) zs2[(quad*4+i2)*ZS2 + wave*16 + li] = C2[i2];
    __syncthreads();                                   // C
    // --- gate2: 256 thr; h2 -> asp2 splits (+ fp32 zst at t=49) ---
    if (tid < 256){
      const int row = tid>>4, chp = tid&15, c0 = 2*chp;
      float2 zi = *(float2*)&zs2[row*ZS2 +      c0];
      float2 zf = *(float2*)&zs2[row*ZS2 + 32 + c0];
      float2 zg = *(float2*)&zs2[row*ZS2 + 64 + c0];
      float2 zo = *(float2*)&zs2[row*ZS2 + 96 + c0];
      float h0, h1v;
      { float ig=sigf(zi.x), fg=sigf(zf.x), gg=fmaxf(zg.x,0.f), og=sigf(zo.x);
        float cn=fg*c2_[0]+ig*gg; c2_[0]=cn; h0=og*fmaxf(cn,0.f); }
      { float ig=sigf(zi.y), fg=sigf(zf.y), gg=fmaxf(zg.y,0.f), og=sigf(zo.y);
        float cn=fg*c2_[1]+ig*gg; c2_[1]=cn; h1v=og*fmaxf(cn,0.f); }
      unsigned ba=__float_as_uint(h0), bb=__float_as_uint(h1v);
      unsigned p0 = (ba>>16) | (bb & 0xFFFF0000u);
      float ra = h0  - __uint_as_float(ba & 0xFFFF0000u);
      float rb = h1v - __uint_as_float(bb & 0xFFFF0000u);
      unsigned p1 = (__float_as_uint(ra)>>16) | (__float_as_uint(rb) & 0xFFFF0000u);
      *(unsigned*)&asp2[0][row*AS2 + c0] = p0;
      *(unsigned*)&asp2[1][row*AS2 + c0] = p1;
      if (t == TT-1){ zst[row*36+c0] = h0; zst[row*36+c0+1] = h1v; }
    }
    // no barrier: loop-back MFMA1 touches only asp1/zs1; barriers A/B cover asp2/zs2
  }
  __syncthreads();
  __builtin_amdgcn_sched_barrier(0);   // keep phase B/C loads out of phase A

  // =================== Phase B: zw3 = b3 + z @ W3 (once, fp32) ===================
  {
    const int g3 = wave>>1, rh3 = wave&1, kh3 = lane>>5, li3 = lane&31;
    const int col3 = g3*64 + 2*li3;
    float zA[16], zB[16];
#pragma unroll
    for (int j=0; j<4; ++j)
#pragma unroll
      for (int e=0; e<4; ++e){
        int k = 4*(2*j+kh3)+e;
        zA[4*j+e] = W3[k*256+col3]; zB[4*j+e] = W3[k*256+col3+1];
      }
    const float bA = b3[col3], bB = b3[col3+1];
#pragma unroll 1
    for (int p=0; p<4; ++p){
      const int r0 = rh3*8 + 2*p, r1 = r0+1;
      const float4* kp0 = (const float4*)&zst[r0*36];
      const float4* kp1 = (const float4*)&zst[r1*36];
      float a0=0.f,a1=0.f,a2=0.f,a3=0.f;
#pragma unroll
      for (int j=0; j<4; ++j){ float4 u=kp0[2*j+kh3], v=kp1[2*j+kh3]; FMA_CHUNK(u,v,4*j,zA,zB) }
      a0 += __shfl_xor(a0,32); a1 += __shfl_xor(a1,32);
      a2 += __shfl_xor(a2,32); a3 += __shfl_xor(a3,32);
      if (kh3==0){
        *(float2*)&zw3[r0*ZS1+col3] = make_float2(a0+bA, a1+bB);
        *(float2*)&zw3[r1*ZS1+col3] = make_float2(a2+bA, a3+bB);
      }
    }
  }
  // Phase-C B-fragments (U3; dense Wd on waves 0/1)
  short8 B3a[2][2], B3b[2][2];
#pragma unroll
  for (int nt=0; nt<2; ++nt)
#pragma unroll
  for (int ks=0; ks<2; ++ks){
    short8 v1, v2;
#pragma unroll
    for (int j=0; j<8; ++j){
      const int k = ks*32 + quad*8 + j;
      const int c = wave*32 + nt*16 + li;
      float w = U3[k*256+c];
      unsigned short s1,s2; split2(w,s1,s2);
      v1[j]=(short)s1; v2[j]=(short)s2;
    }
    B3a[nt][ks]=v1; B3b[nt][ks]=v2;
  }
  short8 Bda[2], Bdb[2];
  const int dcol = wave*16 + li;
  float bdv = 0.f;
  if (wave < 2){
    if (dcol < 24) bdv = bd[dcol];
#pragma unroll
    for (int ks=0; ks<2; ++ks){
      short8 v1, v2;
#pragma unroll
      for (int j=0; j<8; ++j){
        const int k = ks*32 + quad*8 + j;
        float w = (dcol<24) ? Wd[k*24+dcol] : 0.f;
        unsigned short s1,s2; split2(w,s1,s2);
        v1[j]=(short)s1; v2[j]=(short)s2;
      }
      Bda[ks]=v1; Bdb[ks]=v2;
    }
  }
  float c3_[2] = {0.f,0.f};
  __syncthreads();

  // =================== Phase C: L3 + fused dense ===================
#pragma unroll 1
  for (int t=0; t<=TT; ++t){
    f32x4 C0 = {0.f,0.f,0.f,0.f}, C1v = {0.f,0.f,0.f,0.f};
    f32x4 Cd = {bdv,bdv,bdv,bdv};
    if (t < TT){
#pragma unroll
      for (int i2=0; i2<4; ++i2){
        C0[i2]  = zw3[(quad*4+i2)*ZS1 + wave*32 + li];
        C1v[i2] = zw3[(quad*4+i2)*ZS1 + wave*32 + 16 + li];
      }
    }
#pragma unroll
    for (int ks=0; ks<2; ++ks){
      const int ab = li*AS3 + ks*32 + quad*8;
      short8 A1 = *(const short8*)&asp3[0][ab];
      short8 A2 = *(const short8*)&asp3[1][ab];
      if (t < TT){
        PROD3(C0,  A1,A2, B3a[0][ks],B3b[0][ks])
        PROD3(C1v, A1,A2, B3a[1][ks],B3b[1][ks])
      }
      if (t > 0 && wave < 2){ PROD3(Cd, A1,A2, Bda[ks],Bdb[ks]) }
    }
    if (t < TT){
#pragma unroll
      for (int i2=0; i2<4; ++i2){
        zs1[(quad*4+i2)*ZS1 + wave*32 + li]      = C0[i2];
        zs1[(quad*4+i2)*ZS1 + wave*32 + 16 + li] = C1v[i2];
      }
    }
    if (t > 0 && wave < 2 && dcol < 24){
#pragma unroll
      for (int i2=0; i2<4; ++i2)
        out[((size_t)(b0+quad*4+i2)*TT + (t-1))*FF + dcol] = Cd[i2];
    }
    __syncthreads();
    if (t < TT){
      const int row = tid>>5, chp = tid&31, c0 = 2*chp;
      float2 zi = *(float2*)&zs1[row*ZS1 +       c0];
      float2 zf = *(float2*)&zs1[row*ZS1 +  64 + c0];
      float2 zg = *(float2*)&zs1[row*ZS1 + 128 + c0];
      float2 zo = *(float2*)&zs1[row*ZS1 + 192 + c0];
      float h0, h1v;
      { float ig=sigf(zi.x), fg=sigf(zf.x), gg=fmaxf(zg.x,0.f), og=sigf(zo.x);
        float cn=fg*c3_[0]+ig*gg; c3_[0]=cn; h0=og*fmaxf(cn,0.f); }
      { float ig=sigf(zi.y), fg=sigf(zf.y), gg=fmaxf(zg.y,0.f), og=sigf(zo.y);
        float cn=fg*c3_[1]+ig*gg; c3_[1]=cn; h1v=og*fmaxf(cn,0.f); }
      unsigned ba=__float_as_uint(h0), bb=__float_as_uint(h1v);
      unsigned p0 = (ba>>16) | (bb & 0xFFFF0000u);
      float ra = h0  - __uint_as_float(ba & 0xFFFF0000u);
      float rb = h1v - __uint_as_float(bb & 0xFFFF0000u);
      unsigned p1 = (__float_as_uint(ra)>>16) | (__float_as_uint(rb) & 0xFFFF0000u);
      *(unsigned*)&asp3[0][row*AS3 + c0] = p0;
      *(unsigned*)&asp3[1][row*AS3 + c0] = p1;
    }
    __syncthreads();
  }
}

extern "C" void kernel_launch(void* const* d_in, const int* in_sizes, int n_in,
                              void* d_out, int out_size, void* d_ws, size_t ws_size,
                              hipStream_t stream){
  const float* x  = (const float*)d_in[0];
  const float* W1 = (const float*)d_in[1];
  const float* U1 = (const float*)d_in[2];
  const float* b1 = (const float*)d_in[3];
  const float* W2 = (const float*)d_in[4];
  const float* U2 = (const float*)d_in[5];
  const float* b2 = (const float*)d_in[6];
  const float* W3 = (const float*)d_in[7];
  const float* U3 = (const float*)d_in[8];
  const float* b3 = (const float*)d_in[9];
  const float* Wd = (const float*)d_in[10];
  const float* bd = (const float*)d_in[11];
  float* out = (float*)d_out;
  (void)d_ws; (void)ws_size; (void)in_sizes; (void)n_in; (void)out_size;

  hipLaunchKernelGGL(ae_k, dim3(512), dim3(512), 0, stream,
                     x, W1, U1, b1, W2, U2, b2, W3, U3, b3, Wd, bd, out);
}

// Round 6
// 341.053 us; speedup vs baseline: 19.0173x; 1.0226x over previous
//
#include <hip/hip_runtime.h>
#include <cstdint>

#define BB 8192
#define TT 50
#define FF 24

typedef __attribute__((ext_vector_type(8))) short short8;
typedef __attribute__((ext_vector_type(4))) float f32x4;

__device__ __forceinline__ float sigf(float x){ return 1.0f/(1.0f + __expf(-x)); }

__device__ __forceinline__ void split2(float w, unsigned short& s1, unsigned short& s2){
  unsigned b = __float_as_uint(w);
  s1 = (unsigned short)(b >> 16);
  float r = w - __uint_as_float(b & 0xFFFF0000u);
  s2 = (unsigned short)(__float_as_uint(r) >> 16);
}

#define MFMA(A,B,C) __builtin_amdgcn_mfma_f32_16x16x32_bf16((A),(B),(C),0,0,0)
#define PROD3(C,A1,A2,Bq1,Bq2) \
  C = MFMA(A1,Bq1,C); C = MFMA(A1,Bq2,C); C = MFMA(A2,Bq1,C);

#define FMA_CHUNK(u,v,kb,WA,WB) \
  a0 = fmaf((u).x, WA[(kb)+0], a0); a1 = fmaf((u).x, WB[(kb)+0], a1); \
  a2 = fmaf((v).x, WA[(kb)+0], a2); a3 = fmaf((v).x, WB[(kb)+0], a3); \
  a0 = fmaf((u).y, WA[(kb)+1], a0); a1 = fmaf((u).y, WB[(kb)+1], a1); \
  a2 = fmaf((v).y, WA[(kb)+1], a2); a3 = fmaf((v).y, WB[(kb)+1], a3); \
  a0 = fmaf((u).z, WA[(kb)+2], a0); a1 = fmaf((u).z, WB[(kb)+2], a1); \
  a2 = fmaf((v).z, WA[(kb)+2], a2); a3 = fmaf((v).z, WB[(kb)+2], a3); \
  a0 = fmaf((u).w, WA[(kb)+3], a0); a1 = fmaf((u).w, WB[(kb)+3], a1); \
  a2 = fmaf((v).w, WA[(kb)+3], a2); a3 = fmaf((v).w, WB[(kb)+3], a3);

// Fully-fused autoencoder, round 6: software-pipelined phase A (2 barriers/t:
// {gate1(t) || gate2(t-1) || x-stage} then {MFMA2(t) + MFMA1(t+1)}),
// wave-specialized gates (waves 0-3: gate1, waves 4-7: gate2+x), phase-C
// zw3 C-init held in registers, t=0 of phase C peeled (h3=0 -> z3=zw3).
// __launch_bounds__(512,4): cap VGPR+AGPR at 128 so TWO blocks fit per CU
// (round 5: 160 total regs -> 1 block/CU -> 22% occupancy, stall-bound).
__global__ __launch_bounds__(512,4) void ae_k(
    const float* __restrict__ x,
    const float* __restrict__ W1, const float* __restrict__ U1, const float* __restrict__ b1,
    const float* __restrict__ W2, const float* __restrict__ U2, const float* __restrict__ b2,
    const float* __restrict__ W3, const float* __restrict__ U3, const float* __restrict__ b3,
    const float* __restrict__ Wd, const float* __restrict__ bd,
    float* __restrict__ out)
{
  constexpr int AS1 = 104, AS2 = 40, AS3 = 72, ZS1 = 260, ZS2 = 132;
  __shared__ __align__(16) unsigned short asp1[2][16*AS1]; // [x(24)|h1(64)|pad]
  __shared__ __align__(16) unsigned short asp2[2][16*AS2]; // [h2(32)|pad]
  __shared__ __align__(16) unsigned short asp3[2][16*AS3]; // [h3(64)|pad]
  __shared__ __align__(16) float zs1[16*ZS1];
  __shared__ __align__(16) float zs2[16*ZS2];
  __shared__ __align__(16) float zw3[16*ZS1];
  __shared__ __align__(16) float zst[16*36];

  const int tid = threadIdx.x, wave = tid>>6, lane = tid&63;
  const int quad = lane>>4, li = lane&15;
  const int b0 = blockIdx.x*16;

  // ---- Phase-A resident B-fragments (AGPR) ----
  short8 B1a[2][3], B1b[2][3];
#pragma unroll
  for (int nt=0; nt<2; ++nt)
#pragma unroll
  for (int ks=0; ks<3; ++ks){
    short8 v1, v2;
#pragma unroll
    for (int j=0; j<8; ++j){
      const int k = ks*32 + quad*8 + j;
      const int c = wave*32 + nt*16 + li;
      float w = (k<24) ? W1[k*256+c] : ((k<88) ? U1[(k-24)*256+c] : 0.f);
      unsigned short s1,s2; split2(w,s1,s2);
      v1[j]=(short)s1; v2[j]=(short)s2;
    }
    B1a[nt][ks]=v1; B1b[nt][ks]=v2;
  }
  short8 B2a[3], B2b[3];
#pragma unroll
  for (int ks=0; ks<3; ++ks){
    short8 v1, v2;
#pragma unroll
    for (int j=0; j<8; ++j){
      const int k = ks*32 + quad*8 + j;
      const int c = wave*16 + li;
      float w = (k<64) ? W2[k*128+c] : U2[(k-64)*128+c];
      unsigned short s1,s2; split2(w,s1,s2);
      v1[j]=(short)s1; v2[j]=(short)s2;
    }
    B2a[ks]=v1; B2b[ks]=v2;
  }
  const float bi1A = b1[wave*32+li], bi1B = b1[wave*32+16+li];
  const float bi2  = b2[wave*16+li];

  for (int i=tid; i<16*AS1; i+=512) ((unsigned int*)asp1)[i] = 0u;
  for (int i=tid; i<16*AS2; i+=512) ((unsigned int*)asp2)[i] = 0u;
  for (int i=tid; i<16*AS3; i+=512) ((unsigned int*)asp3)[i] = 0u;
  __syncthreads();
  if (tid < 16*FF){
    int r = tid/FF, f = tid - r*FF;
    unsigned short s1,s2; split2(x[((size_t)(b0+r)*TT + 0)*FF + f], s1,s2);
    asp1[0][r*AS1+f]=s1; asp1[1][r*AS1+f]=s2;
  }
  float c1_[4] = {0.f,0.f,0.f,0.f};
  float c2_[2] = {0.f,0.f};
  __syncthreads();

  // ---- Prologue: MFMA1(0) -> zs1 ----
  {
    f32x4 C0 = {bi1A,bi1A,bi1A,bi1A}, C1v = {bi1B,bi1B,bi1B,bi1B};
#pragma unroll
    for (int ks=0; ks<3; ++ks){
      const int ab = li*AS1 + ks*32 + quad*8;
      short8 A1 = *(const short8*)&asp1[0][ab];
      short8 A2 = *(const short8*)&asp1[1][ab];
      PROD3(C0,  A1,A2, B1a[0][ks],B1b[0][ks])
      PROD3(C1v, A1,A2, B1a[1][ks],B1b[1][ks])
    }
#pragma unroll
    for (int i2=0; i2<4; ++i2){
      zs1[(quad*4+i2)*ZS1 + wave*32 + li]      = C0[i2];
      zs1[(quad*4+i2)*ZS1 + wave*32 + 16 + li] = C1v[i2];
    }
  }
  __syncthreads();

  // =================== Phase A: pipelined L1+L2, 2 barriers/t ===================
#pragma unroll 1
  for (int t=0; t<TT; ++t){
    // --- gate phase: gate1(t) on waves 0-3 || gate2(t-1)+x(t+1) on waves 4-7 ---
    if (wave < 4){
      const int row = tid>>4, c0 = 4*(tid&15);
      float4 zi = *(float4*)&zs1[row*ZS1 +       c0];
      float4 zf = *(float4*)&zs1[row*ZS1 +  64 + c0];
      float4 zg = *(float4*)&zs1[row*ZS1 + 128 + c0];
      float4 zo = *(float4*)&zs1[row*ZS1 + 192 + c0];
      float h[4];
      { float ig=sigf(zi.x), fg=sigf(zf.x), gg=fmaxf(zg.x,0.f), og=sigf(zo.x);
        float cn=fg*c1_[0]+ig*gg; c1_[0]=cn; h[0]=og*fmaxf(cn,0.f); }
      { float ig=sigf(zi.y), fg=sigf(zf.y), gg=fmaxf(zg.y,0.f), og=sigf(zo.y);
        float cn=fg*c1_[1]+ig*gg; c1_[1]=cn; h[1]=og*fmaxf(cn,0.f); }
      { float ig=sigf(zi.z), fg=sigf(zf.z), gg=fmaxf(zg.z,0.f), og=sigf(zo.z);
        float cn=fg*c1_[2]+ig*gg; c1_[2]=cn; h[2]=og*fmaxf(cn,0.f); }
      { float ig=sigf(zi.w), fg=sigf(zf.w), gg=fmaxf(zg.w,0.f), og=sigf(zo.w);
        float cn=fg*c1_[3]+ig*gg; c1_[3]=cn; h[3]=og*fmaxf(cn,0.f); }
      unsigned bb0=__float_as_uint(h[0]), bb1=__float_as_uint(h[1]);
      unsigned bb2=__float_as_uint(h[2]), bb3=__float_as_uint(h[3]);
      uint2 P0 = { (bb0>>16)|(bb1&0xFFFF0000u), (bb2>>16)|(bb3&0xFFFF0000u) };
      unsigned rb0=__float_as_uint(h[0]-__uint_as_float(bb0&0xFFFF0000u));
      unsigned rb1=__float_as_uint(h[1]-__uint_as_float(bb1&0xFFFF0000u));
      unsigned rb2=__float_as_uint(h[2]-__uint_as_float(bb2&0xFFFF0000u));
      unsigned rb3=__float_as_uint(h[3]-__uint_as_float(bb3&0xFFFF0000u));
      uint2 P1 = { (rb0>>16)|(rb1&0xFFFF0000u), (rb2>>16)|(rb3&0xFFFF0000u) };
      *(uint2*)&asp1[0][row*AS1 + 24 + c0] = P0;
      *(uint2*)&asp1[1][row*AS1 + 24 + c0] = P1;
    } else {
      const int tid2 = tid - 256;
      if (t > 0){
        const int row = tid2>>4, c0 = 2*(tid2&15);
        float2 zi = *(float2*)&zs2[row*ZS2 +      c0];
        float2 zf = *(float2*)&zs2[row*ZS2 + 32 + c0];
        float2 zg = *(float2*)&zs2[row*ZS2 + 64 + c0];
        float2 zo = *(float2*)&zs2[row*ZS2 + 96 + c0];
        float h0, h1v;
        { float ig=sigf(zi.x), fg=sigf(zf.x), gg=fmaxf(zg.x,0.f), og=sigf(zo.x);
          float cn=fg*c2_[0]+ig*gg; c2_[0]=cn; h0=og*fmaxf(cn,0.f); }
        { float ig=sigf(zi.y), fg=sigf(zf.y), gg=fmaxf(zg.y,0.f), og=sigf(zo.y);
          float cn=fg*c2_[1]+ig*gg; c2_[1]=cn; h1v=og*fmaxf(cn,0.f); }
        unsigned ba=__float_as_uint(h0), bb=__float_as_uint(h1v);
        unsigned p0 = (ba>>16) | (bb & 0xFFFF0000u);
        float ra = h0  - __uint_as_float(ba & 0xFFFF0000u);
        float rb = h1v - __uint_as_float(bb & 0xFFFF0000u);
        unsigned p1 = (__float_as_uint(ra)>>16) | (__float_as_uint(rb) & 0xFFFF0000u);
        *(unsigned*)&asp2[0][row*AS2 + c0] = p0;
        *(unsigned*)&asp2[1][row*AS2 + c0] = p1;
      }
      if (t+1 < TT){
#pragma unroll
        for (int e=0; e<2; ++e){
          const int i = tid2 + 256*e;
          if (i < 16*FF){
            int r = i/FF, f = i - r*FF;
            unsigned short s1,s2;
            split2(x[((size_t)(b0+r)*TT + (t+1))*FF + f], s1,s2);
            asp1[0][r*AS1+f]=s1; asp1[1][r*AS1+f]=s2;
          }
        }
      }
    }
    __syncthreads();
    // --- MFMA phase: MFMA2(t) + MFMA1(t+1) ---
    {
      f32x4 C2 = {bi2,bi2,bi2,bi2};
#pragma unroll
      for (int ks=0; ks<2; ++ks){
        const int ab = li*AS1 + 24 + ks*32 + quad*8;
        short8 A1 = *(const short8*)&asp1[0][ab];
        short8 A2 = *(const short8*)&asp1[1][ab];
        PROD3(C2, A1,A2, B2a[ks],B2b[ks])
      }
      {
        const int ab = li*AS2 + quad*8;
        short8 A1 = *(const short8*)&asp2[0][ab];
        short8 A2 = *(const short8*)&asp2[1][ab];
        PROD3(C2, A1,A2, B2a[2],B2b[2])
      }
#pragma unroll
      for (int i2=0; i2<4; ++i2) zs2[(quad*4+i2)*ZS2 + wave*16 + li] = C2[i2];
    }
    if (t+1 < TT){
      f32x4 C0 = {bi1A,bi1A,bi1A,bi1A}, C1v = {bi1B,bi1B,bi1B,bi1B};
#pragma unroll
      for (int ks=0; ks<3; ++ks){
        const int ab = li*AS1 + ks*32 + quad*8;
        short8 A1 = *(const short8*)&asp1[0][ab];
        short8 A2 = *(const short8*)&asp1[1][ab];
        PROD3(C0,  A1,A2, B1a[0][ks],B1b[0][ks])
        PROD3(C1v, A1,A2, B1a[1][ks],B1b[1][ks])
      }
#pragma unroll
      for (int i2=0; i2<4; ++i2){
        zs1[(quad*4+i2)*ZS1 + wave*32 + li]      = C0[i2];
        zs1[(quad*4+i2)*ZS1 + wave*32 + 16 + li] = C1v[i2];
      }
    }
    __syncthreads();
  }
  // ---- epilogue: gate2(TT-1) -> h2 -> zst ----
  if (wave >= 4){
    const int tid2 = tid - 256;
    const int row = tid2>>4, c0 = 2*(tid2&15);
    float2 zi = *(float2*)&zs2[row*ZS2 +      c0];
    float2 zf = *(float2*)&zs2[row*ZS2 + 32 + c0];
    float2 zg = *(float2*)&zs2[row*ZS2 + 64 + c0];
    float2 zo = *(float2*)&zs2[row*ZS2 + 96 + c0];
    float h0, h1v;
    { float ig=sigf(zi.x), fg=sigf(zf.x), gg=fmaxf(zg.x,0.f), og=sigf(zo.x);
      float cn=fg*c2_[0]+ig*gg; h0=og*fmaxf(cn,0.f); }
    { float ig=sigf(zi.y), fg=sigf(zf.y), gg=fmaxf(zg.y,0.f), og=sigf(zo.y);
      float cn=fg*c2_[1]+ig*gg; h1v=og*fmaxf(cn,0.f); }
    zst[row*36 + c0] = h0; zst[row*36 + c0 + 1] = h1v;
  }
  __syncthreads();
  __builtin_amdgcn_sched_barrier(0);   // keep phase B/C loads out of phase A

  // =================== Phase B: zw3 = b3 + z @ W3 (once, fp32) ===================
  {
    const int g3 = wave>>1, rh3 = wave&1, kh3 = lane>>5, li3 = lane&31;
    const int col3 = g3*64 + 2*li3;
    float zA[16], zB[16];
#pragma unroll
    for (int j=0; j<4; ++j)
#pragma unroll
      for (int e=0; e<4; ++e){
        int k = 4*(2*j+kh3)+e;
        zA[4*j+e] = W3[k*256+col3]; zB[4*j+e] = W3[k*256+col3+1];
      }
    const float bA = b3[col3], bB = b3[col3+1];
#pragma unroll 1
    for (int p=0; p<4; ++p){
      const int r0 = rh3*8 + 2*p, r1 = r0+1;
      const float4* kp0 = (const float4*)&zst[r0*36];
      const float4* kp1 = (const float4*)&zst[r1*36];
      float a0=0.f,a1=0.f,a2=0.f,a3=0.f;
#pragma unroll
      for (int j=0; j<4; ++j){ float4 u=kp0[2*j+kh3], v=kp1[2*j+kh3]; FMA_CHUNK(u,v,4*j,zA,zB) }
      a0 += __shfl_xor(a0,32); a1 += __shfl_xor(a1,32);
      a2 += __shfl_xor(a2,32); a3 += __shfl_xor(a3,32);
      if (kh3==0){
        *(float2*)&zw3[r0*ZS1+col3] = make_float2(a0+bA, a1+bB);
        *(float2*)&zw3[r1*ZS1+col3] = make_float2(a2+bA, a3+bB);
      }
    }
  }
  // Phase-C B-fragments (U3; dense Wd on waves 0/1)
  short8 B3a[2][2], B3b[2][2];
#pragma unroll
  for (int nt=0; nt<2; ++nt)
#pragma unroll
  for (int ks=0; ks<2; ++ks){
    short8 v1, v2;
#pragma unroll
    for (int j=0; j<8; ++j){
      const int k = ks*32 + quad*8 + j;
      const int c = wave*32 + nt*16 + li;
      float w = U3[k*256+c];
      unsigned short s1,s2; split2(w,s1,s2);
      v1[j]=(short)s1; v2[j]=(short)s2;
    }
    B3a[nt][ks]=v1; B3b[nt][ks]=v2;
  }
  short8 Bda[2], Bdb[2];
  const int dcol = wave*16 + li;
  float bdv = 0.f;
  if (wave < 2){
    if (dcol < 24) bdv = bd[dcol];
#pragma unroll
    for (int ks=0; ks<2; ++ks){
      short8 v1, v2;
#pragma unroll
      for (int j=0; j<8; ++j){
        const int k = ks*32 + quad*8 + j;
        float w = (dcol<24) ? Wd[k*24+dcol] : 0.f;
        unsigned short s1,s2; split2(w,s1,s2);
        v1[j]=(short)s1; v2[j]=(short)s2;
      }
      Bda[ks]=v1; Bdb[ks]=v2;
    }
  }
  float c3_[2] = {0.f,0.f};
  __syncthreads();

  // zw3 C-init into registers (loop-invariant)
  float zr0[4], zr1[4];
#pragma unroll
  for (int i2=0; i2<4; ++i2){
    zr0[i2] = zw3[(quad*4+i2)*ZS1 + wave*32 + li];
    zr1[i2] = zw3[(quad*4+i2)*ZS1 + wave*32 + 16 + li];
  }
  // ---- peeled t=0: h3 = 0 -> z3(0) = zw3, gate directly ----
  {
    const int row = tid>>5, c0 = 2*(tid&31);
    float2 zi = *(float2*)&zw3[row*ZS1 +       c0];
    float2 zf = *(float2*)&zw3[row*ZS1 +  64 + c0];
    float2 zg = *(float2*)&zw3[row*ZS1 + 128 + c0];
    float2 zo = *(float2*)&zw3[row*ZS1 + 192 + c0];
    float h0, h1v;
    { float ig=sigf(zi.x), fg=sigf(zf.x), gg=fmaxf(zg.x,0.f), og=sigf(zo.x);
      float cn=ig*gg; c3_[0]=cn; h0=og*fmaxf(cn,0.f); (void)fg; }
    { float ig=sigf(zi.y), fg=sigf(zf.y), gg=fmaxf(zg.y,0.f), og=sigf(zo.y);
      float cn=ig*gg; c3_[1]=cn; h1v=og*fmaxf(cn,0.f); (void)fg; }
    unsigned ba=__float_as_uint(h0), bb=__float_as_uint(h1v);
    unsigned p0 = (ba>>16) | (bb & 0xFFFF0000u);
    float ra = h0  - __uint_as_float(ba & 0xFFFF0000u);
    float rb = h1v - __uint_as_float(bb & 0xFFFF0000u);
    unsigned p1 = (__float_as_uint(ra)>>16) | (__float_as_uint(rb) & 0xFFFF0000u);
    *(unsigned*)&asp3[0][row*AS3 + c0] = p0;
    *(unsigned*)&asp3[1][row*AS3 + c0] = p1;
  }
  __syncthreads();

  // =================== Phase C: L3 + fused dense, t = 1..TT-1 ===================
#pragma unroll 1
  for (int t=1; t<TT; ++t){
    f32x4 C0 = {zr0[0],zr0[1],zr0[2],zr0[3]};
    f32x4 C1v = {zr1[0],zr1[1],zr1[2],zr1[3]};
    f32x4 Cd = {bdv,bdv,bdv,bdv};
#pragma unroll
    for (int ks=0; ks<2; ++ks){
      const int ab = li*AS3 + ks*32 + quad*8;
      short8 A1 = *(const short8*)&asp3[0][ab];
      short8 A2 = *(const short8*)&asp3[1][ab];
      PROD3(C0,  A1,A2, B3a[0][ks],B3b[0][ks])
      PROD3(C1v, A1,A2, B3a[1][ks],B3b[1][ks])
      if (wave < 2){ PROD3(Cd, A1,A2, Bda[ks],Bdb[ks]) }
    }
#pragma unroll
    for (int i2=0; i2<4; ++i2){
      zs1[(quad*4+i2)*ZS1 + wave*32 + li]      = C0[i2];
      zs1[(quad*4+i2)*ZS1 + wave*32 + 16 + li] = C1v[i2];
    }
    if (wave < 2 && dcol < 24){
#pragma unroll
      for (int i2=0; i2<4; ++i2)
        out[((size_t)(b0+quad*4+i2)*TT + (t-1))*FF + dcol] = Cd[i2];
    }
    __syncthreads();
    {
      const int row = tid>>5, c0 = 2*(tid&31);
      float2 zi = *(float2*)&zs1[row*ZS1 +       c0];
      float2 zf = *(float2*)&zs1[row*ZS1 +  64 + c0];
      float2 zg = *(float2*)&zs1[row*ZS1 + 128 + c0];
      float2 zo = *(float2*)&zs1[row*ZS1 + 192 + c0];
      float h0, h1v;
      { float ig=sigf(zi.x), fg=sigf(zf.x), gg=fmaxf(zg.x,0.f), og=sigf(zo.x);
        float cn=fg*c3_[0]+ig*gg; c3_[0]=cn; h0=og*fmaxf(cn,0.f); }
      { float ig=sigf(zi.y), fg=sigf(zf.y), gg=fmaxf(zg.y,0.f), og=sigf(zo.y);
        float cn=fg*c3_[1]+ig*gg; c3_[1]=cn; h1v=og*fmaxf(cn,0.f); }
      unsigned ba=__float_as_uint(h0), bb=__float_as_uint(h1v);
      unsigned p0 = (ba>>16) | (bb & 0xFFFF0000u);
      float ra = h0  - __uint_as_float(ba & 0xFFFF0000u);
      float rb = h1v - __uint_as_float(bb & 0xFFFF0000u);
      unsigned p1 = (__float_as_uint(ra)>>16) | (__float_as_uint(rb) & 0xFFFF0000u);
      *(unsigned*)&asp3[0][row*AS3 + c0] = p0;
      *(unsigned*)&asp3[1][row*AS3 + c0] = p1;
    }
    __syncthreads();
  }
  // ---- final dense for t = TT-1 ----
  if (wave < 2){
    f32x4 Cd = {bdv,bdv,bdv,bdv};
#pragma unroll
    for (int ks=0; ks<2; ++ks){
      const int ab = li*AS3 + ks*32 + quad*8;
      short8 A1 = *(const short8*)&asp3[0][ab];
      short8 A2 = *(const short8*)&asp3[1][ab];
      PROD3(Cd, A1,A2, Bda[ks],Bdb[ks])
    }
    if (dcol < 24){
#pragma unroll
      for (int i2=0; i2<4; ++i2)
        out[((size_t)(b0+quad*4+i2)*TT + (TT-1))*FF + dcol] = Cd[i2];
    }
  }
}

extern "C" void kernel_launch(void* const* d_in, const int* in_sizes, int n_in,
                              void* d_out, int out_size, void* d_ws, size_t ws_size,
                              hipStream_t stream){
  const float* x  = (const float*)d_in[0];
  const float* W1 = (const float*)d_in[1];
  const float* U1 = (const float*)d_in[2];
  const float* b1 = (const float*)d_in[3];
  const float* W2 = (const float*)d_in[4];
  const float* U2 = (const float*)d_in[5];
  const float* b2 = (const float*)d_in[6];
  const float* W3 = (const float*)d_in[7];
  const float* U3 = (const float*)d_in[8];
  const float* b3 = (const float*)d_in[9];
  const float* Wd = (const float*)d_in[10];
  const float* bd = (const float*)d_in[11];
  float* out = (float*)d_out;
  (void)d_ws; (void)ws_size; (void)in_sizes; (void)n_in; (void)out_size;

  hipLaunchKernelGGL(ae_k, dim3(512), dim3(512), 0, stream,
                     x, W1, U1, b1, W2, U2, b2, W3, U3, b3, Wd, bd, out);
}